// Round 12
// baseline (422.816 us; speedup 1.0000x reference)
//
#include <hip/hip_runtime.h>
#include <math.h>

#define D_DIM 128

using bf16x8 = __attribute__((ext_vector_type(8))) short;
using f32x4  = __attribute__((ext_vector_type(4))) float;

__device__ __forceinline__ unsigned short f2bf(float f) {
    unsigned u = __float_as_uint(f);
    u += 0x7fffu + ((u >> 16) & 1u);   // RNE
    return (unsigned short)(u >> 16);
}

// ---------------- type sort: ballot-based stable partition (no global atomics) ----------------
__global__ __launch_bounds__(256)
void count_types_k(const int* __restrict__ nt, int* __restrict__ blockcnt, int N) {
    __shared__ int wcnt[4][4];
    int tid = threadIdx.x;
    int i = blockIdx.x * 256 + tid;
    int w = tid >> 6, l = tid & 63;
    int t = (i < N) ? nt[i] : -1;
    #pragma unroll
    for (int tt = 0; tt < 4; ++tt) {
        unsigned long long m = __ballot(t == tt);
        if (l == 0) wcnt[w][tt] = __popcll(m);
    }
    __syncthreads();
    if (tid < 4) {
        blockcnt[blockIdx.x * 4 + tid] =
            wcnt[0][tid] + wcnt[1][tid] + wcnt[2][tid] + wcnt[3][tid];
    }
}

__global__ __launch_bounds__(256)
void scan_blocks_k(const int* __restrict__ blockcnt, int nb, int N,
                   int* __restrict__ boff, int* __restrict__ pad_off,
                   int* __restrict__ order_p) {
    __shared__ int tot_s[4];
    __shared__ int po_s[5];
    int tid = threadIdx.x;
    int t = tid >> 6, l = tid & 63;
    int sum = 0;
    for (int base = 0; base < nb; base += 64) {
        int b = base + l;
        sum += (b < nb) ? blockcnt[b * 4 + t] : 0;
    }
    #pragma unroll
    for (int m = 1; m < 64; m <<= 1) sum += __shfl_xor(sum, m);
    if (l == 0) tot_s[t] = sum;
    __syncthreads();
    if (tid == 0) {
        int s = 0;
        for (int tt = 0; tt < 4; ++tt) { po_s[tt] = s; s += ((tot_s[tt] + 63) >> 6) << 6; }
        po_s[4] = s;
        for (int tt = 0; tt < 5; ++tt) pad_off[tt] = po_s[tt];
    }
    __syncthreads();
    // fill pad slots with -1 (bounded by allocation N+320 — round-10 overflow lesson)
    #pragma unroll 1
    for (int tt = 0; tt < 4; ++tt) {
        int gs = po_s[tt] + tot_s[tt], ge = po_s[tt + 1];
        for (int i = gs + tid; i < ge; i += 256) order_p[i] = -1;
    }
    for (int i = po_s[4] + tid; i < N + 320; i += 256) order_p[i] = -1;
    __syncthreads();
    int run = po_s[t];
    for (int base = 0; base < nb; base += 64) {
        int b = base + l;
        int v = (b < nb) ? blockcnt[b * 4 + t] : 0;
        int incl = v;
        #pragma unroll
        for (int off = 1; off < 64; off <<= 1) {
            int up = __shfl_up(incl, off);
            if (l >= off) incl += up;
        }
        if (b < nb) boff[b * 4 + t] = run + incl - v;
        run += __shfl(incl, 63);
    }
}

__global__ __launch_bounds__(256)
void scatter_types_k(const int* __restrict__ nt, const int* __restrict__ boff,
                     int* __restrict__ order_p, int* __restrict__ inv, int N) {
    __shared__ int wbase[4][4];
    int tid = threadIdx.x;
    int i = blockIdx.x * 256 + tid;
    int w = tid >> 6, l = tid & 63;
    int t = (i < N) ? nt[i] : -1;
    int rank = 0;
    #pragma unroll
    for (int tt = 0; tt < 4; ++tt) {
        unsigned long long m = __ballot(t == tt);
        if (l == 0) wbase[w][tt] = __popcll(m);
        if (t == tt) rank = __popcll(m & ((1ull << l) - 1ull));
    }
    __syncthreads();
    if (tid < 4) {
        int run = 0;
        for (int ww = 0; ww < 4; ++ww) { int c = wbase[ww][tid]; wbase[ww][tid] = run; run += c; }
    }
    __syncthreads();
    if (i < N) {
        int p = boff[blockIdx.x * 4 + t] + wbase[w][t] + rank;
        order_p[p] = i;
        inv[i] = p;
    }
}

// ---------------- fused weight prep: Wq/Wa transpose + Wk·rel_att + Wv·rel_msg + biases ----------------
__global__ __launch_bounds__(256)
void prep_weights_k(const float* __restrict__ Wk, const float* __restrict__ Wq,
                    const float* __restrict__ Wv, const float* __restrict__ Wa,
                    const float* __restrict__ bk, const float* __restrict__ bv,
                    const float* __restrict__ rel_att, const float* __restrict__ rel_msg,
                    const float* __restrict__ rel_pri,
                    unsigned short* __restrict__ Wqt, unsigned short* __restrict__ Wat,
                    unsigned short* __restrict__ Wkrt, unsigned short* __restrict__ Wvmt,
                    float* __restrict__ bkr, float* __restrict__ bvm) {
    int idx = blockIdx.x * 256 + threadIdx.x;  // 262144 = 16*128*128
    int i = idx & 127;
    int col = (idx >> 7) & 127;
    int r = (idx >> 14) & 3;
    int t = idx >> 16;
    int h = col >> 4, k = col & 15;
    {
        const float* wk = Wk + t * 16384 + i * 128 + h * 16;
        const float* wv = Wv + t * 16384 + i * 128 + h * 16;
        const float* ra = rel_att + ((r * 8 + h) * 16) * 16 + k;
        const float* rm = rel_msg + ((r * 8 + h) * 16) * 16 + k;
        float s1 = 0.f, s2 = 0.f;
        #pragma unroll
        for (int d = 0; d < 16; ++d) {
            s1 += wk[d] * ra[d * 16];
            s2 += wv[d] * rm[d * 16];
        }
        Wkrt[idx] = f2bf(s1 * rel_pri[r * 8 + h] * 0.25f);
        Wvmt[idx] = f2bf(s2);
    }
    if (idx < 65536) {
        int t2 = idx >> 14, rem = idx & 16383, row = rem >> 7, col2 = rem & 127;
        int d = (t2 << 14) | (col2 << 7) | row;
        Wqt[d] = f2bf(Wq[idx]);
        Wat[d] = f2bf(Wa[idx]);
    }
    if (idx < 4096) {
        int bi = idx & 2047;
        int col3 = bi & 127, r3 = (bi >> 7) & 3, t3 = bi >> 9;
        int h3 = col3 >> 4, k3 = col3 & 15;
        float s = 0.f;
        if (idx < 2048) {
            #pragma unroll
            for (int d = 0; d < 16; ++d)
                s += bk[t3 * 128 + h3 * 16 + d] * rel_att[((r3 * 8 + h3) * 16 + d) * 16 + k3];
            bkr[bi] = s * rel_pri[r3 * 8 + h3] * 0.25f;
        } else {
            #pragma unroll
            for (int d = 0; d < 16; ++d)
                s += bv[t3 * 128 + h3 * 16 + d] * rel_msg[((r3 * 8 + h3) * 16 + d) * 16 + k3];
            bvm[bi] = s;
        }
    }
}

// ---------------- dst-CSR build ----------------
__global__ void deg_k(const int* __restrict__ ei, int* __restrict__ deg, int E) {
    int e = blockIdx.x * 256 + threadIdx.x;
    if (e < E) atomicAdd(&deg[ei[E + e]], 1);
}
__global__ void scan1_k(const int* __restrict__ deg, int* __restrict__ excl,
                        int* __restrict__ bsum, int N) {
    __shared__ int s[512];
    int i = blockIdx.x * 512 + threadIdx.x;
    int v = (i < N) ? deg[i] : 0;
    s[threadIdx.x] = v;
    __syncthreads();
    for (int off = 1; off < 512; off <<= 1) {
        int t = (threadIdx.x >= off) ? s[threadIdx.x - off] : 0;
        __syncthreads();
        s[threadIdx.x] += t;
        __syncthreads();
    }
    if (i < N) excl[i] = s[threadIdx.x] - v;
    if (threadIdx.x == 511) bsum[blockIdx.x] = s[511];
}
__global__ void scan2_k(int* __restrict__ bsum, int nb) {
    int l = threadIdx.x & 63;
    int run = 0;
    for (int base = 0; base < nb; base += 64) {
        int b = base + l;
        int v = (b < nb) ? bsum[b] : 0;
        int incl = v;
        #pragma unroll
        for (int off = 1; off < 64; off <<= 1) {
            int up = __shfl_up(incl, off);
            if (l >= off) incl += up;
        }
        if (b < nb) bsum[b] = run + incl - v;
        run += __shfl(incl, 63);
    }
}
__global__ void scan3_k(int* __restrict__ excl, const int* __restrict__ bsum, int N) {
    int i = blockIdx.x * 512 + threadIdx.x;
    if (i < N) excl[i] += bsum[blockIdx.x];
}
__global__ void scatter_edges_k(const int* __restrict__ ei, const int* __restrict__ et,
                                const int* __restrict__ inv,
                                const int* __restrict__ off, int* __restrict__ cursor,
                                int* __restrict__ elist, int E) {
    int e = blockIdx.x * 256 + threadIdx.x;
    if (e < E) {
        int dst = ei[E + e];
        int p = off[dst] + atomicAdd(&cursor[dst], 1);
        elist[p] = (inv[ei[e]] << 2) | et[e];   // permuted src row + relation
    }
}

// ---------------- MFMA projection (weight-shared, PERMUTED contiguous stores) ----------------
__global__ __launch_bounds__(256, 4)
void proj_mfma(const float* __restrict__ x, const int* __restrict__ order_p,
               const int* __restrict__ pad_off,
               const unsigned short* __restrict__ Wqt, const float* __restrict__ bq,
               const unsigned short* __restrict__ W_kr_t, const float* __restrict__ bkr,
               const unsigned short* __restrict__ W_vm_t, const float* __restrict__ bvm,
               unsigned short* __restrict__ Qb, unsigned short* __restrict__ KRb,
               unsigned short* __restrict__ VMb, int N) {
    __shared__ unsigned shmem[64 * 128];  // 32 KB: x staging, then output stage
    __shared__ int gid_s[64];
    unsigned* xs = shmem;
    char* stageb = (char*)shmem;
    int tid = threadIdx.x;
    int base = blockIdx.x * 64;
    int t = (base >= pad_off[1]) + (base >= pad_off[2]) + (base >= pad_off[3]);

    if (tid < 64) gid_s[tid] = order_p[base + tid];
    __syncthreads();

    {   // stage x -> bf16 swizzled LDS
        int row = tid >> 2, q = tid & 3;
        int g = gid_s[row];
        const float4* xr = (const float4*)(x + (size_t)(g < 0 ? 0 : g) * 128 + q * 32);
        int swz = (row & 7) << 4;
        #pragma unroll
        for (int v4 = 0; v4 < 8; ++v4) {
            float4 f = (g >= 0) ? xr[v4] : make_float4(0.f, 0.f, 0.f, 0.f);
            unsigned ua = (unsigned)f2bf(f.x) | ((unsigned)f2bf(f.y) << 16);
            unsigned ub = (unsigned)f2bf(f.z) | ((unsigned)f2bf(f.w) << 16);
            int c2 = (q * 16 + v4 * 2) * 4;
            xs[(row << 6) + (((c2) ^ swz) >> 2)] = ua;
            xs[(row << 6) + (((c2 + 4) ^ swz) >> 2)] = ub;
        }
    }
    __syncthreads();

    int w = tid >> 6, l = tid & 63;
    int lr = l & 15, lg = l >> 4;

    bf16x8 afr[4][4];
    #pragma unroll
    for (int j = 0; j < 4; ++j) {
        int row = j * 16 + lr;
        #pragma unroll
        for (int ks = 0; ks < 4; ++ks) {
            int byteoff = (ks * 64 + lg * 16) ^ ((lr & 7) << 4);
            afr[j][ks] = *reinterpret_cast<const bf16x8*>(
                reinterpret_cast<const char*>(&xs[row << 6]) + byteoff);
        }
    }
    __syncthreads();

    #pragma unroll 1
    for (int pass = 0; pass < 4; ++pass) {
        int m0 = (pass & 1) * 2;
        const unsigned short* Wp;
        const float* bp;
        unsigned short* dstp;
        if (pass < 2) { Wp = W_kr_t; bp = bkr; dstp = KRb; }
        else          { Wp = W_vm_t; bp = bvm; dstp = VMb; }
        Wp += (size_t)(t * 4 + m0) << 14;
        bp += (t * 4 + m0) * 128;

        #pragma unroll
        for (int ci = 0; ci < 2; ++ci) {
            int c = w * 2 + ci;
            #pragma unroll
            for (int mm = 0; mm < 2; ++mm) {
                const unsigned short* wb = Wp + ((size_t)mm << 14)
                                         + (size_t)(c * 16 + lr) * 128 + lg * 8;
                bf16x8 wfr[4];
                #pragma unroll
                for (int ks = 0; ks < 4; ++ks) wfr[ks] = *(const bf16x8*)(wb + ks * 32);
                f32x4 acc0 = {0.f,0.f,0.f,0.f}, acc1 = {0.f,0.f,0.f,0.f};
                f32x4 acc2 = {0.f,0.f,0.f,0.f}, acc3 = {0.f,0.f,0.f,0.f};
                #pragma unroll
                for (int ks = 0; ks < 4; ++ks) {
                    acc0 = __builtin_amdgcn_mfma_f32_16x16x32_bf16(wfr[ks], afr[0][ks], acc0, 0, 0, 0);
                    acc1 = __builtin_amdgcn_mfma_f32_16x16x32_bf16(wfr[ks], afr[1][ks], acc1, 0, 0, 0);
                    acc2 = __builtin_amdgcn_mfma_f32_16x16x32_bf16(wfr[ks], afr[2][ks], acc2, 0, 0, 0);
                    acc3 = __builtin_amdgcn_mfma_f32_16x16x32_bf16(wfr[ks], afr[3][ks], acc3, 0, 0, 0);
                }
                float4 bb = *(const float4*)&bp[mm * 128 + c * 16 + lg * 4];
                int colb = (mm * 128 + c * 16 + lg * 4) * 2;
                f32x4 accs[4] = {acc0, acc1, acc2, acc3};
                #pragma unroll
                for (int j = 0; j < 4; ++j) {
                    int node = j * 16 + lr;
                    unsigned p0 = (unsigned)f2bf(accs[j][0] + bb.x) | ((unsigned)f2bf(accs[j][1] + bb.y) << 16);
                    unsigned p1 = (unsigned)f2bf(accs[j][2] + bb.z) | ((unsigned)f2bf(accs[j][3] + bb.w) << 16);
                    int byte = (node * 512 + colb) ^ ((node & 7) << 4);
                    *(uint2*)(stageb + byte) = make_uint2(p0, p1);
                }
            }
        }
        __syncthreads();
        // contiguous drain: row index = base + local row (permuted space)
        #pragma unroll
        for (int i = 0; i < 8; ++i) {
            int row = w * 16 + i * 2 + (l >> 5);
            int l32 = l & 31;
            int byte = (row * 512 + l32 * 16) ^ ((row & 7) << 4);
            uint4 v = *(const uint4*)(stageb + byte);
            *(uint4*)&dstp[(size_t)(base + row) * 512 + (pass & 1) * 256 + l32 * 8] = v;
        }
        __syncthreads();
    }

    #pragma unroll
    for (int ci = 0; ci < 2; ++ci) {
        int c = w * 2 + ci;
        const unsigned short* wb = Wqt + ((size_t)t << 14) + (size_t)(c * 16 + lr) * 128 + lg * 8;
        bf16x8 wfr[4];
        #pragma unroll
        for (int ks = 0; ks < 4; ++ks) wfr[ks] = *(const bf16x8*)(wb + ks * 32);
        f32x4 acc0 = {0.f,0.f,0.f,0.f}, acc1 = {0.f,0.f,0.f,0.f};
        f32x4 acc2 = {0.f,0.f,0.f,0.f}, acc3 = {0.f,0.f,0.f,0.f};
        #pragma unroll
        for (int ks = 0; ks < 4; ++ks) {
            acc0 = __builtin_amdgcn_mfma_f32_16x16x32_bf16(wfr[ks], afr[0][ks], acc0, 0, 0, 0);
            acc1 = __builtin_amdgcn_mfma_f32_16x16x32_bf16(wfr[ks], afr[1][ks], acc1, 0, 0, 0);
            acc2 = __builtin_amdgcn_mfma_f32_16x16x32_bf16(wfr[ks], afr[2][ks], acc2, 0, 0, 0);
            acc3 = __builtin_amdgcn_mfma_f32_16x16x32_bf16(wfr[ks], afr[3][ks], acc3, 0, 0, 0);
        }
        float4 bb = *(const float4*)&bq[t * 128 + c * 16 + lg * 4];
        int colb = (c * 16 + lg * 4) * 2;
        f32x4 accs[4] = {acc0, acc1, acc2, acc3};
        #pragma unroll
        for (int j = 0; j < 4; ++j) {
            int node = j * 16 + lr;
            unsigned p0 = (unsigned)f2bf(accs[j][0] + bb.x) | ((unsigned)f2bf(accs[j][1] + bb.y) << 16);
            unsigned p1 = (unsigned)f2bf(accs[j][2] + bb.z) | ((unsigned)f2bf(accs[j][3] + bb.w) << 16);
            int byte = (node * 256 + colb) ^ ((node & 7) << 4);
            *(uint2*)(stageb + byte) = make_uint2(p0, p1);
        }
    }
    __syncthreads();
    #pragma unroll
    for (int i = 0; i < 4; ++i) {
        int row = w * 16 + i * 4 + (l >> 4);
        int l16 = l & 15;
        int byte = (row * 256 + l16 * 16) ^ ((row & 7) << 4);
        uint4 v = *(const uint4*)(stageb + byte);
        *(uint4*)&Qb[(size_t)(base + row) * 128 + l16 * 8] = v;
    }
}

// ---------------- fused edge kernel: TWO dsts per wave, interleaved chains ----------------
__global__ __launch_bounds__(256)
void edge_fused(const unsigned short* __restrict__ Qb,
                const unsigned short* __restrict__ KRb,
                const unsigned short* __restrict__ VMb,
                const int* __restrict__ inv,
                const int* __restrict__ off, const int* __restrict__ elist,
                float* __restrict__ aggr, int N, int E) {
    int w = threadIdx.x >> 6, l = threadIdx.x & 63;
    int dstA = (blockIdx.x * 4 + w) * 2;
    if (dstA >= N) return;
    int dstB = dstA + 1;
    bool hasB = (dstB < N);
    int q = l >> 4, c = l & 15;

    int pA = inv[dstA];
    int pB = hasB ? inv[dstB] : pA;

    float QfA[8], QfB[8];
    {
        bf16x8 qv = *(const bf16x8*)&Qb[(size_t)pA * 128 + c * 8];
        const unsigned* qu = (const unsigned*)&qv;
        #pragma unroll
        for (int i = 0; i < 4; ++i) {
            QfA[2*i]   = __uint_as_float(qu[i] << 16);
            QfA[2*i+1] = __uint_as_float(qu[i] & 0xffff0000u);
        }
    }
    {
        bf16x8 qv = *(const bf16x8*)&Qb[(size_t)pB * 128 + c * 8];
        const unsigned* qu = (const unsigned*)&qv;
        #pragma unroll
        for (int i = 0; i < 4; ++i) {
            QfB[2*i]   = __uint_as_float(qu[i] << 16);
            QfB[2*i+1] = __uint_as_float(qu[i] & 0xffff0000u);
        }
    }

    int eA0 = off[dstA];
    int eA1 = hasB ? off[dstB] : E;
    int eB0 = eA1;
    int eB1 = hasB ? ((dstB == N - 1) ? E : off[dstB + 1]) : eA1;
    int degA = eA1 - eA0;
    int degB = eB1 - eB0;
    int mdeg = max(degA, degB);

    float SA[8] = {0.f,0.f,0.f,0.f,0.f,0.f,0.f,0.f};
    float SB[8] = {0.f,0.f,0.f,0.f,0.f,0.f,0.f,0.f};
    float denA = 0.f, denB = 0.f;

    for (int base = 0; base < mdeg; base += 64) {
        int cntA = min(64, degA - base);
        int cntB = min(64, degB - base);
        int pkA_l = (degA > 0) ? elist[eA0 + min(base + l, degA - 1)] : 0;
        int pkB_l = (degB > 0) ? elist[eB0 + min(base + l, degB - 1)] : 0;
        int mcnt = max(cntA, cntB);
        for (int s = 0; s < mcnt; s += 8) {
            int clA = max(cntA - 1, 0), clB = max(cntB - 1, 0);
            int pkA0 = __shfl(pkA_l, min(s + q, clA));
            int pkA1 = __shfl(pkA_l, min(s + 4 + q, clA));
            int pkB0 = __shfl(pkB_l, min(s + q, clB));
            int pkB1 = __shfl(pkB_l, min(s + 4 + q, clB));
            bf16x8 krA0 = *(const bf16x8*)&KRb[(size_t)pkA0 * 128 + c * 8];
            bf16x8 krA1 = *(const bf16x8*)&KRb[(size_t)pkA1 * 128 + c * 8];
            bf16x8 krB0 = *(const bf16x8*)&KRb[(size_t)pkB0 * 128 + c * 8];
            bf16x8 krB1 = *(const bf16x8*)&KRb[(size_t)pkB1 * 128 + c * 8];
            bf16x8 vmA0 = *(const bf16x8*)&VMb[(size_t)pkA0 * 128 + c * 8];
            bf16x8 vmA1 = *(const bf16x8*)&VMb[(size_t)pkA1 * 128 + c * 8];
            bf16x8 vmB0 = *(const bf16x8*)&VMb[(size_t)pkB0 * 128 + c * 8];
            bf16x8 vmB1 = *(const bf16x8*)&VMb[(size_t)pkB1 * 128 + c * 8];

            const unsigned* ka0 = (const unsigned*)&krA0;
            const unsigned* ka1 = (const unsigned*)&krA1;
            const unsigned* kb0 = (const unsigned*)&krB0;
            const unsigned* kb1 = (const unsigned*)&krB1;
            float dA0 = 0.f, dA1 = 0.f, dB0 = 0.f, dB1 = 0.f;
            #pragma unroll
            for (int i = 0; i < 4; ++i) {
                dA0 = fmaf(QfA[2*i],   __uint_as_float(ka0[i] << 16), dA0);
                dA0 = fmaf(QfA[2*i+1], __uint_as_float(ka0[i] & 0xffff0000u), dA0);
                dA1 = fmaf(QfA[2*i],   __uint_as_float(ka1[i] << 16), dA1);
                dA1 = fmaf(QfA[2*i+1], __uint_as_float(ka1[i] & 0xffff0000u), dA1);
                dB0 = fmaf(QfB[2*i],   __uint_as_float(kb0[i] << 16), dB0);
                dB0 = fmaf(QfB[2*i+1], __uint_as_float(kb0[i] & 0xffff0000u), dB0);
                dB1 = fmaf(QfB[2*i],   __uint_as_float(kb1[i] << 16), dB1);
                dB1 = fmaf(QfB[2*i+1], __uint_as_float(kb1[i] & 0xffff0000u), dB1);
            }
            dA0 += __shfl_xor(dA0, 1);
            dA1 += __shfl_xor(dA1, 1);
            dB0 += __shfl_xor(dB0, 1);
            dB1 += __shfl_xor(dB1, 1);
            float wA0 = (s + q < cntA)     ? __expf(dA0) : 0.f;
            float wA1 = (s + 4 + q < cntA) ? __expf(dA1) : 0.f;
            float wB0 = (s + q < cntB)     ? __expf(dB0) : 0.f;
            float wB1 = (s + 4 + q < cntB) ? __expf(dB1) : 0.f;
            denA += wA0 + wA1;
            denB += wB0 + wB1;

            const unsigned* va0 = (const unsigned*)&vmA0;
            const unsigned* va1 = (const unsigned*)&vmA1;
            const unsigned* vb0 = (const unsigned*)&vmB0;
            const unsigned* vb1 = (const unsigned*)&vmB1;
            #pragma unroll
            for (int i = 0; i < 4; ++i) {
                SA[2*i]   = fmaf(wA0, __uint_as_float(va0[i] << 16), SA[2*i]);
                SA[2*i+1] = fmaf(wA0, __uint_as_float(va0[i] & 0xffff0000u), SA[2*i+1]);
                SA[2*i]   = fmaf(wA1, __uint_as_float(va1[i] << 16), SA[2*i]);
                SA[2*i+1] = fmaf(wA1, __uint_as_float(va1[i] & 0xffff0000u), SA[2*i+1]);
                SB[2*i]   = fmaf(wB0, __uint_as_float(vb0[i] << 16), SB[2*i]);
                SB[2*i+1] = fmaf(wB0, __uint_as_float(vb0[i] & 0xffff0000u), SB[2*i+1]);
                SB[2*i]   = fmaf(wB1, __uint_as_float(vb1[i] << 16), SB[2*i]);
                SB[2*i+1] = fmaf(wB1, __uint_as_float(vb1[i] & 0xffff0000u), SB[2*i+1]);
            }
        }
    }

    #pragma unroll
    for (int m = 16; m <= 32; m <<= 1) {
        denA += __shfl_xor(denA, m);
        denB += __shfl_xor(denB, m);
        #pragma unroll
        for (int i = 0; i < 8; ++i) {
            SA[i] += __shfl_xor(SA[i], m);
            SB[i] += __shfl_xor(SB[i], m);
        }
    }
    float invA = (denA > 0.f) ? 1.f / denA : 0.f;
    float invB = (denB > 0.f) ? 1.f / denB : 0.f;
    float o[8];
    #pragma unroll
    for (int i = 0; i < 8; ++i) o[i] = (q == 1) ? SB[i] * invB : SA[i] * invA;
    int sd = (q == 1) ? dstB : dstA;
    if (q == 0 || (q == 1 && hasB)) {
        *(float4*)&aggr[(size_t)sd * 128 + c * 8]     = make_float4(o[0], o[1], o[2], o[3]);
        *(float4*)&aggr[(size_t)sd * 128 + c * 8 + 4] = make_float4(o[4], o[5], o[6], o[7]);
    }
}

// ---------------- MFMA gelu + Wa proj + skip + LayerNorm (transposed D, aggr aliases d_out) ----------------
__global__ __launch_bounds__(256)
void node_out_mfma(const float* __restrict__ aggr, const float* __restrict__ x,
                   const int* __restrict__ order_p, const int* __restrict__ pad_off,
                   const unsigned short* __restrict__ Wat, const float* __restrict__ ba,
                   const float* __restrict__ skip, const float* __restrict__ gamma,
                   const float* __restrict__ beta, float* __restrict__ out, int N) {
    __shared__ unsigned hsm[64 * 64];
    __shared__ int gid_s[64];
    int tid = threadIdx.x;
    int base = blockIdx.x * 64;
    int t = (base >= pad_off[1]) + (base >= pad_off[2]) + (base >= pad_off[3]);

    if (tid < 64) gid_s[tid] = order_p[base + tid];
    __syncthreads();

    {
        int row = tid >> 2, q = tid & 3;
        int g = gid_s[row];
        const float4* ar = (const float4*)(aggr + (size_t)(g < 0 ? 0 : g) * 128 + q * 32);
        int swz = (row & 7) << 4;
        #pragma unroll
        for (int v4 = 0; v4 < 8; ++v4) {
            float4 f = (g >= 0) ? ar[v4] : make_float4(0.f, 0.f, 0.f, 0.f);
            float g0 = 0.5f * f.x * (1.f + erff(f.x * 0.70710678118654752f));
            float g1 = 0.5f * f.y * (1.f + erff(f.y * 0.70710678118654752f));
            float g2 = 0.5f * f.z * (1.f + erff(f.z * 0.70710678118654752f));
            float g3 = 0.5f * f.w * (1.f + erff(f.w * 0.70710678118654752f));
            unsigned ua = (unsigned)f2bf(g0) | ((unsigned)f2bf(g1) << 16);
            unsigned ub = (unsigned)f2bf(g2) | ((unsigned)f2bf(g3) << 16);
            int c2 = (q * 16 + v4 * 2) * 4;
            hsm[(row << 6) + (((c2) ^ swz) >> 2)] = ua;
            hsm[(row << 6) + (((c2 + 4) ^ swz) >> 2)] = ub;
        }
    }
    __syncthreads();

    int w = tid >> 6, l = tid & 63;
    int rowbase = w * 16, lr = l & 15, lg = l >> 4;
    int myrow = rowbase + lr;

    bf16x8 afr[4];
    #pragma unroll
    for (int ks = 0; ks < 4; ++ks) {
        int byteoff = (ks * 64 + lg * 16) ^ ((lr & 7) << 4);
        afr[ks] = *reinterpret_cast<const bf16x8*>(
            reinterpret_cast<const char*>(&hsm[myrow << 6]) + byteoff);
    }

    float al = 1.f / (1.f + __expf(-skip[t]));
    int g = gid_s[myrow];

    float pre[8][4];
    float s = 0.f, sq = 0.f;

    #pragma unroll
    for (int c = 0; c < 8; ++c) {
        const unsigned short* wb = Wat + ((size_t)t << 14) + (size_t)(c * 16 + lr) * 128 + lg * 8;
        f32x4 acc = {0.f, 0.f, 0.f, 0.f};
        #pragma unroll
        for (int ks = 0; ks < 4; ++ks)
            acc = __builtin_amdgcn_mfma_f32_16x16x32_bf16(
                *(const bf16x8*)(wb + ks * 32), afr[ks], acc, 0, 0, 0);
        float4 bav = *(const float4*)&ba[t * 128 + c * 16 + lg * 4];
        float4 xv = (g >= 0) ? *(const float4*)&x[(size_t)g * 128 + c * 16 + lg * 4]
                             : make_float4(0.f, 0.f, 0.f, 0.f);
        float p0 = (acc[0] + bav.x) * al + xv.x * (1.f - al);
        float p1 = (acc[1] + bav.y) * al + xv.y * (1.f - al);
        float p2 = (acc[2] + bav.z) * al + xv.z * (1.f - al);
        float p3 = (acc[3] + bav.w) * al + xv.w * (1.f - al);
        pre[c][0] = p0; pre[c][1] = p1; pre[c][2] = p2; pre[c][3] = p3;
        s += p0 + p1 + p2 + p3;
        sq += p0 * p0 + p1 * p1 + p2 * p2 + p3 * p3;
    }

    s  += __shfl_xor(s, 16);  sq += __shfl_xor(sq, 16);
    s  += __shfl_xor(s, 32);  sq += __shfl_xor(sq, 32);
    float mu = s * (1.f / 128.f);
    float var = sq * (1.f / 128.f) - mu * mu;
    float rs = rsqrtf(fmaxf(var, 0.f) + 1e-5f);

    #pragma unroll
    for (int c = 0; c < 8; ++c) {
        float4 ga = *(const float4*)&gamma[t * 128 + c * 16 + lg * 4];
        float4 be = *(const float4*)&beta[t * 128 + c * 16 + lg * 4];
        float4 o;
        o.x = (pre[c][0] - mu) * rs * ga.x + be.x;
        o.y = (pre[c][1] - mu) * rs * ga.y + be.y;
        o.z = (pre[c][2] - mu) * rs * ga.z + be.z;
        o.w = (pre[c][3] - mu) * rs * ga.w + be.w;
        if (g >= 0) *(float4*)&out[(size_t)g * 128 + c * 16 + lg * 4] = o;
    }
}

extern "C" void kernel_launch(void* const* d_in, const int* in_sizes, int n_in,
                              void* d_out, int out_size, void* d_ws, size_t ws_size,
                              hipStream_t stream) {
    const float* x   = (const float*)d_in[0];
    const int*   nt  = (const int*)d_in[1];
    const int*   ei  = (const int*)d_in[2];
    const int*   et  = (const int*)d_in[3];
    const float* Wk = (const float*)d_in[5];  const float* bk = (const float*)d_in[6];
    const float* Wq = (const float*)d_in[7];  const float* bq = (const float*)d_in[8];
    const float* Wv = (const float*)d_in[9];  const float* bv = (const float*)d_in[10];
    const float* Wa = (const float*)d_in[11]; const float* ba = (const float*)d_in[12];
    const float* rel_pri = (const float*)d_in[13];
    const float* rel_att = (const float*)d_in[14];
    const float* rel_msg = (const float*)d_in[15];
    const float* skip    = (const float*)d_in[16];
    const float* gamma   = (const float*)d_in[17];
    const float* beta    = (const float*)d_in[18];

    const int N = in_sizes[0] / 128;
    const int E = in_sizes[3];
    const int NB = (N + 511) / 512;
    const int NB256 = (N + 255) / 256;
    const int NP = N + 320;   // padded permuted-row count

    unsigned short* Qb  = (unsigned short*)d_ws;           // NP*128 bf16 (permuted)
    unsigned short* KRb = Qb + (size_t)NP * 128;           // NP*512 bf16 (permuted)
    unsigned short* VMb = KRb + (size_t)NP * 512;          // NP*512 bf16 (permuted)
    unsigned short* Wqt = VMb + (size_t)NP * 512;          // 65536
    unsigned short* Wat = Wqt + 65536;                     // 65536
    unsigned short* Wkrt = Wat + 65536;                    // 262144
    unsigned short* Wvmt = Wkrt + 262144;                  // 262144
    float* bkr = (float*)(Wvmt + 262144);                  // 2048
    float* bvm = bkr + 2048;                               // 2048
    int* order_p = (int*)(bvm + 2048);                     // NP
    int* inv      = order_p + NP;                          // N
    int* blockcnt = inv + N;                               // NB256*4
    int* boff     = blockcnt + NB256 * 4;                  // NB256*4
    int* pad_off  = boff + NB256 * 4;                      // 8
    int* deg     = pad_off + 8;                            // N  (deg, cursorD adjacent: one memset)
    int* cursorD = deg + N;                                // N
    int* off     = cursorD + N;                            // N
    int* bsum    = off + N;                                // NB+8
    int* elist   = bsum + NB + 8;                          // E
    float* aggr  = (float*)d_out;                          // aliases output (safe: see node_out)

    hipMemsetAsync(deg, 0, (size_t)(2 * N) * sizeof(int), stream);

    count_types_k<<<NB256, 256, 0, stream>>>(nt, blockcnt, N);
    scan_blocks_k<<<1, 256, 0, stream>>>(blockcnt, NB256, N, boff, pad_off, order_p);
    scatter_types_k<<<NB256, 256, 0, stream>>>(nt, boff, order_p, inv, N);

    prep_weights_k<<<1024, 256, 0, stream>>>(Wk, Wq, Wv, Wa, bk, bv, rel_att, rel_msg,
                                             rel_pri, Wqt, Wat, Wkrt, Wvmt, bkr, bvm);

    deg_k<<<(E + 255) / 256, 256, 0, stream>>>(ei, deg, E);
    scan1_k<<<NB, 512, 0, stream>>>(deg, off, bsum, N);
    scan2_k<<<1, 64, 0, stream>>>(bsum, NB);
    scan3_k<<<NB, 512, 0, stream>>>(off, bsum, N);
    scatter_edges_k<<<(E + 255) / 256, 256, 0, stream>>>(ei, et, inv, off, cursorD, elist, E);

    int nb64 = (N + 252 + 63) / 64;
    proj_mfma<<<nb64, 256, 0, stream>>>(x, order_p, pad_off, Wqt, bq, Wkrt, bkr, Wvmt, bvm,
                                        Qb, KRb, VMb, N);
    int npairs = (N + 1) / 2;
    edge_fused<<<(npairs + 3) / 4, 256, 0, stream>>>(Qb, KRb, VMb, inv, off, elist, aggr, N, E);
    node_out_mfma<<<nb64, 256, 0, stream>>>(aggr, x, order_p, pad_off, Wat, ba, skip,
                                            gamma, beta, (float*)d_out, N);
}

// Round 14
// 392.317 us; speedup vs baseline: 1.0777x; 1.0777x over previous
//
#include <hip/hip_runtime.h>
#include <math.h>

#define D_DIM 128

using bf16x8 = __attribute__((ext_vector_type(8))) short;
using f32x4  = __attribute__((ext_vector_type(4))) float;

__device__ __forceinline__ unsigned short f2bf(float f) {
    unsigned u = __float_as_uint(f);
    u += 0x7fffu + ((u >> 16) & 1u);   // RNE
    return (unsigned short)(u >> 16);
}

// ---------------- type sort: ballot-based stable partition (no global atomics) ----------------
__global__ __launch_bounds__(256)
void count_types_k(const int* __restrict__ nt, int* __restrict__ blockcnt, int N) {
    __shared__ int wcnt[4][4];
    int tid = threadIdx.x;
    int i = blockIdx.x * 256 + tid;
    int w = tid >> 6, l = tid & 63;
    int t = (i < N) ? nt[i] : -1;
    #pragma unroll
    for (int tt = 0; tt < 4; ++tt) {
        unsigned long long m = __ballot(t == tt);
        if (l == 0) wcnt[w][tt] = __popcll(m);
    }
    __syncthreads();
    if (tid < 4) {
        blockcnt[blockIdx.x * 4 + tid] =
            wcnt[0][tid] + wcnt[1][tid] + wcnt[2][tid] + wcnt[3][tid];
    }
}

__global__ __launch_bounds__(256)
void scan_blocks_k(const int* __restrict__ blockcnt, int nb, int N,
                   int* __restrict__ boff, int* __restrict__ pad_off,
                   int* __restrict__ order_p) {
    __shared__ int tot_s[4];
    __shared__ int po_s[5];
    int tid = threadIdx.x;
    int t = tid >> 6, l = tid & 63;
    int sum = 0;
    for (int base = 0; base < nb; base += 64) {
        int b = base + l;
        sum += (b < nb) ? blockcnt[b * 4 + t] : 0;
    }
    #pragma unroll
    for (int m = 1; m < 64; m <<= 1) sum += __shfl_xor(sum, m);
    if (l == 0) tot_s[t] = sum;
    __syncthreads();
    if (tid == 0) {
        int s = 0;
        for (int tt = 0; tt < 4; ++tt) { po_s[tt] = s; s += ((tot_s[tt] + 63) >> 6) << 6; }
        po_s[4] = s;
        for (int tt = 0; tt < 5; ++tt) pad_off[tt] = po_s[tt];
    }
    __syncthreads();
    // fill pad slots with -1 (bounded by allocation N+320 — round-10 overflow lesson)
    #pragma unroll 1
    for (int tt = 0; tt < 4; ++tt) {
        int gs = po_s[tt] + tot_s[tt], ge = po_s[tt + 1];
        for (int i = gs + tid; i < ge; i += 256) order_p[i] = -1;
    }
    for (int i = po_s[4] + tid; i < N + 320; i += 256) order_p[i] = -1;
    __syncthreads();
    int run = po_s[t];
    for (int base = 0; base < nb; base += 64) {
        int b = base + l;
        int v = (b < nb) ? blockcnt[b * 4 + t] : 0;
        int incl = v;
        #pragma unroll
        for (int off = 1; off < 64; off <<= 1) {
            int up = __shfl_up(incl, off);
            if (l >= off) incl += up;
        }
        if (b < nb) boff[b * 4 + t] = run + incl - v;
        run += __shfl(incl, 63);
    }
}

__global__ __launch_bounds__(256)
void scatter_types_k(const int* __restrict__ nt, const int* __restrict__ boff,
                     int* __restrict__ order_p, int N) {
    __shared__ int wbase[4][4];
    int tid = threadIdx.x;
    int i = blockIdx.x * 256 + tid;
    int w = tid >> 6, l = tid & 63;
    int t = (i < N) ? nt[i] : -1;
    int rank = 0;
    #pragma unroll
    for (int tt = 0; tt < 4; ++tt) {
        unsigned long long m = __ballot(t == tt);
        if (l == 0) wbase[w][tt] = __popcll(m);
        if (t == tt) rank = __popcll(m & ((1ull << l) - 1ull));
    }
    __syncthreads();
    if (tid < 4) {
        int run = 0;
        for (int ww = 0; ww < 4; ++ww) { int c = wbase[ww][tid]; wbase[ww][tid] = run; run += c; }
    }
    __syncthreads();
    if (i < N) order_p[boff[blockIdx.x * 4 + t] + wbase[w][t] + rank] = i;
}

// ---------------- fused weight prep ----------------
__global__ __launch_bounds__(256)
void prep_weights_k(const float* __restrict__ Wk, const float* __restrict__ Wq,
                    const float* __restrict__ Wv, const float* __restrict__ Wa,
                    const float* __restrict__ bk, const float* __restrict__ bv,
                    const float* __restrict__ rel_att, const float* __restrict__ rel_msg,
                    const float* __restrict__ rel_pri,
                    unsigned short* __restrict__ Wqt, unsigned short* __restrict__ Wat,
                    unsigned short* __restrict__ Wkrt, unsigned short* __restrict__ Wvmt,
                    float* __restrict__ bkr, float* __restrict__ bvm) {
    int idx = blockIdx.x * 256 + threadIdx.x;  // 262144 = 16*128*128
    int i = idx & 127;
    int col = (idx >> 7) & 127;
    int r = (idx >> 14) & 3;
    int t = idx >> 16;
    int h = col >> 4, k = col & 15;
    {
        const float* wk = Wk + t * 16384 + i * 128 + h * 16;
        const float* wv = Wv + t * 16384 + i * 128 + h * 16;
        const float* ra = rel_att + ((r * 8 + h) * 16) * 16 + k;
        const float* rm = rel_msg + ((r * 8 + h) * 16) * 16 + k;
        float s1 = 0.f, s2 = 0.f;
        #pragma unroll
        for (int d = 0; d < 16; ++d) {
            s1 += wk[d] * ra[d * 16];
            s2 += wv[d] * rm[d * 16];
        }
        Wkrt[idx] = f2bf(s1 * rel_pri[r * 8 + h] * 0.25f);
        Wvmt[idx] = f2bf(s2);
    }
    if (idx < 65536) {
        int t2 = idx >> 14, rem = idx & 16383, row = rem >> 7, col2 = rem & 127;
        int d = (t2 << 14) | (col2 << 7) | row;
        Wqt[d] = f2bf(Wq[idx]);
        Wat[d] = f2bf(Wa[idx]);
    }
    if (idx < 4096) {
        int bi = idx & 2047;
        int col3 = bi & 127, r3 = (bi >> 7) & 3, t3 = bi >> 9;
        int h3 = col3 >> 4, k3 = col3 & 15;
        float s = 0.f;
        if (idx < 2048) {
            #pragma unroll
            for (int d = 0; d < 16; ++d)
                s += bk[t3 * 128 + h3 * 16 + d] * rel_att[((r3 * 8 + h3) * 16 + d) * 16 + k3];
            bkr[bi] = s * rel_pri[r3 * 8 + h3] * 0.25f;
        } else {
            #pragma unroll
            for (int d = 0; d < 16; ++d)
                s += bv[t3 * 128 + h3 * 16 + d] * rel_msg[((r3 * 8 + h3) * 16 + d) * 16 + k3];
            bvm[bi] = s;
        }
    }
}

// ---------------- dst-CSR build ----------------
__global__ void deg_k(const int* __restrict__ ei, int* __restrict__ deg, int E) {
    int e = blockIdx.x * 256 + threadIdx.x;
    if (e < E) atomicAdd(&deg[ei[E + e]], 1);
}
__global__ void scan1_k(const int* __restrict__ deg, int* __restrict__ excl,
                        int* __restrict__ bsum, int N) {
    __shared__ int s[512];
    int i = blockIdx.x * 512 + threadIdx.x;
    int v = (i < N) ? deg[i] : 0;
    s[threadIdx.x] = v;
    __syncthreads();
    for (int off = 1; off < 512; off <<= 1) {
        int t = (threadIdx.x >= off) ? s[threadIdx.x - off] : 0;
        __syncthreads();
        s[threadIdx.x] += t;
        __syncthreads();
    }
    if (i < N) excl[i] = s[threadIdx.x] - v;
    if (threadIdx.x == 511) bsum[blockIdx.x] = s[511];
}
// fused scan2+scan3: each block reduces its bsum prefix itself (<=~200 ints)
__global__ void scan23_k(int* __restrict__ excl, const int* __restrict__ bsum, int N) {
    __shared__ int pre_s;
    int b = blockIdx.x;
    int tid = threadIdx.x, l = tid & 63;
    if (tid < 64) {
        int sum = 0;
        for (int j = l; j < b; j += 64) sum += bsum[j];
        #pragma unroll
        for (int m = 1; m < 64; m <<= 1) sum += __shfl_xor(sum, m);
        if (l == 0) pre_s = sum;
    }
    __syncthreads();
    int i = b * 512 + tid;
    if (i < N) excl[i] += pre_s;
}
__global__ void scatter_edges_k(const int* __restrict__ ei, const int* __restrict__ et,
                                const int* __restrict__ off, int* __restrict__ cursor,
                                int* __restrict__ elist, int E) {
    int e = blockIdx.x * 256 + threadIdx.x;
    if (e < E) {
        int dst = ei[E + e];
        int p = off[dst] + atomicAdd(&cursor[dst], 1);
        elist[p] = (ei[e] << 2) | et[e];
    }
}

// ---------------- MFMA projection (weight-shared): Q + interleaved KR/VM rows ----------------
// KVb row pk = g*4 + r (256 shorts): [0:128]=KR[r], [128:256]=VM[r]
__global__ __launch_bounds__(256, 4)
void proj_mfma(const float* __restrict__ x, const int* __restrict__ order_p,
               const int* __restrict__ pad_off,
               const unsigned short* __restrict__ Wqt, const float* __restrict__ bq,
               const unsigned short* __restrict__ W_kr_t, const float* __restrict__ bkr,
               const unsigned short* __restrict__ W_vm_t, const float* __restrict__ bvm,
               unsigned short* __restrict__ Qb, unsigned short* __restrict__ KVb, int N) {
    __shared__ unsigned shmem[64 * 128];  // 32 KB: x staging, then output stage
    __shared__ int gid_s[64];
    unsigned* xs = shmem;
    char* stageb = (char*)shmem;
    int tid = threadIdx.x;
    int base = blockIdx.x * 64;
    int t = (base >= pad_off[1]) + (base >= pad_off[2]) + (base >= pad_off[3]);

    if (tid < 64) gid_s[tid] = order_p[base + tid];
    __syncthreads();

    {   // stage x -> bf16 swizzled LDS
        int row = tid >> 2, q = tid & 3;
        int g = gid_s[row];
        const float4* xr = (const float4*)(x + (size_t)(g < 0 ? 0 : g) * 128 + q * 32);
        int swz = (row & 7) << 4;
        #pragma unroll
        for (int v4 = 0; v4 < 8; ++v4) {
            float4 f = (g >= 0) ? xr[v4] : make_float4(0.f, 0.f, 0.f, 0.f);
            unsigned ua = (unsigned)f2bf(f.x) | ((unsigned)f2bf(f.y) << 16);
            unsigned ub = (unsigned)f2bf(f.z) | ((unsigned)f2bf(f.w) << 16);
            int c2 = (q * 16 + v4 * 2) * 4;
            xs[(row << 6) + (((c2) ^ swz) >> 2)] = ua;
            xs[(row << 6) + (((c2 + 4) ^ swz) >> 2)] = ub;
        }
    }
    __syncthreads();

    int w = tid >> 6, l = tid & 63;
    int lr = l & 15, lg = l >> 4;

    bf16x8 afr[4][4];
    #pragma unroll
    for (int j = 0; j < 4; ++j) {
        int row = j * 16 + lr;
        #pragma unroll
        for (int ks = 0; ks < 4; ++ks) {
            int byteoff = (ks * 64 + lg * 16) ^ ((lr & 7) << 4);
            afr[j][ks] = *reinterpret_cast<const bf16x8*>(
                reinterpret_cast<const char*>(&xs[row << 6]) + byteoff);
        }
    }
    __syncthreads();

    #pragma unroll 1
    for (int pass = 0; pass < 4; ++pass) {
        bool isKR = (pass < 2);
        int m0 = (pass & 1) * 2;
        const unsigned short* Wp = (isKR ? W_kr_t : W_vm_t) + ((size_t)(t * 4 + m0) << 14);
        const float* bp = (isKR ? bkr : bvm) + (t * 4 + m0) * 128;

        #pragma unroll
        for (int ci = 0; ci < 2; ++ci) {
            int c = w * 2 + ci;
            #pragma unroll
            for (int mm = 0; mm < 2; ++mm) {
                const unsigned short* wb = Wp + ((size_t)mm << 14)
                                         + (size_t)(c * 16 + lr) * 128 + lg * 8;
                bf16x8 wfr[4];
                #pragma unroll
                for (int ks = 0; ks < 4; ++ks) wfr[ks] = *(const bf16x8*)(wb + ks * 32);
                f32x4 acc0 = {0.f,0.f,0.f,0.f}, acc1 = {0.f,0.f,0.f,0.f};
                f32x4 acc2 = {0.f,0.f,0.f,0.f}, acc3 = {0.f,0.f,0.f,0.f};
                #pragma unroll
                for (int ks = 0; ks < 4; ++ks) {
                    acc0 = __builtin_amdgcn_mfma_f32_16x16x32_bf16(wfr[ks], afr[0][ks], acc0, 0, 0, 0);
                    acc1 = __builtin_amdgcn_mfma_f32_16x16x32_bf16(wfr[ks], afr[1][ks], acc1, 0, 0, 0);
                    acc2 = __builtin_amdgcn_mfma_f32_16x16x32_bf16(wfr[ks], afr[2][ks], acc2, 0, 0, 0);
                    acc3 = __builtin_amdgcn_mfma_f32_16x16x32_bf16(wfr[ks], afr[3][ks], acc3, 0, 0, 0);
                }
                float4 bb = *(const float4*)&bp[mm * 128 + c * 16 + lg * 4];
                int colb = (mm * 128 + c * 16 + lg * 4) * 2;
                f32x4 accs[4] = {acc0, acc1, acc2, acc3};
                #pragma unroll
                for (int j = 0; j < 4; ++j) {
                    int node = j * 16 + lr;
                    unsigned p0 = (unsigned)f2bf(accs[j][0] + bb.x) | ((unsigned)f2bf(accs[j][1] + bb.y) << 16);
                    unsigned p1 = (unsigned)f2bf(accs[j][2] + bb.z) | ((unsigned)f2bf(accs[j][3] + bb.w) << 16);
                    int byte = (node * 512 + colb) ^ ((node & 7) << 4);
                    *(uint2*)(stageb + byte) = make_uint2(p0, p1);
                }
            }
        }
        __syncthreads();
        // drain: stage holds [node][mat(0/1)][128 cols]; write to interleaved KVb rows
        #pragma unroll
        for (int i = 0; i < 8; ++i) {
            int row = w * 16 + i * 2 + (l >> 5);
            int l32 = l & 31;
            int byte = (row * 512 + l32 * 16) ^ ((row & 7) << 4);
            uint4 v = *(const uint4*)(stageb + byte);
            int g = gid_s[row];
            if (g >= 0) {
                int mat = m0 + (l32 >> 4);
                int coloff = (l32 & 15) * 8 + (isKR ? 0 : 128);
                *(uint4*)&KVb[((size_t)g * 4 + mat) * 256 + coloff] = v;
            }
        }
        __syncthreads();
    }

    // ---- Q pass ----
    #pragma unroll
    for (int ci = 0; ci < 2; ++ci) {
        int c = w * 2 + ci;
        const unsigned short* wb = Wqt + ((size_t)t << 14) + (size_t)(c * 16 + lr) * 128 + lg * 8;
        bf16x8 wfr[4];
        #pragma unroll
        for (int ks = 0; ks < 4; ++ks) wfr[ks] = *(const bf16x8*)(wb + ks * 32);
        f32x4 acc0 = {0.f,0.f,0.f,0.f}, acc1 = {0.f,0.f,0.f,0.f};
        f32x4 acc2 = {0.f,0.f,0.f,0.f}, acc3 = {0.f,0.f,0.f,0.f};
        #pragma unroll
        for (int ks = 0; ks < 4; ++ks) {
            acc0 = __builtin_amdgcn_mfma_f32_16x16x32_bf16(wfr[ks], afr[0][ks], acc0, 0, 0, 0);
            acc1 = __builtin_amdgcn_mfma_f32_16x16x32_bf16(wfr[ks], afr[1][ks], acc1, 0, 0, 0);
            acc2 = __builtin_amdgcn_mfma_f32_16x16x32_bf16(wfr[ks], afr[2][ks], acc2, 0, 0, 0);
            acc3 = __builtin_amdgcn_mfma_f32_16x16x32_bf16(wfr[ks], afr[3][ks], acc3, 0, 0, 0);
        }
        float4 bb = *(const float4*)&bq[t * 128 + c * 16 + lg * 4];
        int colb = (c * 16 + lg * 4) * 2;
        f32x4 accs[4] = {acc0, acc1, acc2, acc3};
        #pragma unroll
        for (int j = 0; j < 4; ++j) {
            int node = j * 16 + lr;
            unsigned p0 = (unsigned)f2bf(accs[j][0] + bb.x) | ((unsigned)f2bf(accs[j][1] + bb.y) << 16);
            unsigned p1 = (unsigned)f2bf(accs[j][2] + bb.z) | ((unsigned)f2bf(accs[j][3] + bb.w) << 16);
            int byte = (node * 256 + colb) ^ ((node & 7) << 4);
            *(uint2*)(stageb + byte) = make_uint2(p0, p1);
        }
    }
    __syncthreads();
    #pragma unroll
    for (int i = 0; i < 4; ++i) {
        int row = w * 16 + i * 4 + (l >> 4);
        int l16 = l & 15;
        int byte = (row * 256 + l16 * 16) ^ ((row & 7) << 4);
        uint4 v = *(const uint4*)(stageb + byte);
        int g = gid_s[row];
        if (g >= 0) *(uint4*)&Qb[(size_t)g * 128 + l16 * 8] = v;
    }
}

// ---------------- fused edge kernel: TWO dsts per wave, single-row KV gathers ----------------
// lane l: quarter q=l>>4 (edge slot), chunk c=l&15 (dims 8c..8c+7)
__global__ __launch_bounds__(256)
void edge_fused(const unsigned short* __restrict__ Qb,
                const unsigned short* __restrict__ KVb,
                const int* __restrict__ off, const int* __restrict__ elist,
                float* __restrict__ aggr, int N, int E) {
    int w = threadIdx.x >> 6, l = threadIdx.x & 63;
    int dstA = (blockIdx.x * 4 + w) * 2;
    if (dstA >= N) return;
    int dstB = dstA + 1;
    bool hasB = (dstB < N);
    int q = l >> 4, c = l & 15;

    float QfA[8], QfB[8];
    {
        bf16x8 qv = *(const bf16x8*)&Qb[(size_t)dstA * 128 + c * 8];
        const unsigned* qu = (const unsigned*)&qv;
        #pragma unroll
        for (int i = 0; i < 4; ++i) {
            QfA[2*i]   = __uint_as_float(qu[i] << 16);
            QfA[2*i+1] = __uint_as_float(qu[i] & 0xffff0000u);
        }
    }
    {
        bf16x8 qv = *(const bf16x8*)&Qb[(size_t)(hasB ? dstB : dstA) * 128 + c * 8];
        const unsigned* qu = (const unsigned*)&qv;
        #pragma unroll
        for (int i = 0; i < 4; ++i) {
            QfB[2*i]   = __uint_as_float(qu[i] << 16);
            QfB[2*i+1] = __uint_as_float(qu[i] & 0xffff0000u);
        }
    }

    int eA0 = off[dstA];
    int eA1 = hasB ? off[dstB] : E;
    int eB0 = eA1;
    int eB1 = hasB ? ((dstB == N - 1) ? E : off[dstB + 1]) : eA1;
    int degA = eA1 - eA0;
    int degB = eB1 - eB0;
    int mdeg = max(degA, degB);

    float SA[8] = {0.f,0.f,0.f,0.f,0.f,0.f,0.f,0.f};
    float SB[8] = {0.f,0.f,0.f,0.f,0.f,0.f,0.f,0.f};
    float denA = 0.f, denB = 0.f;

    for (int base = 0; base < mdeg; base += 64) {
        int cntA = min(64, degA - base);
        int cntB = min(64, degB - base);
        int pkA_l = (degA > 0) ? elist[eA0 + min(base + l, degA - 1)] : 0;
        int pkB_l = (degB > 0) ? elist[eB0 + min(base + l, degB - 1)] : 0;
        int mcnt = max(cntA, cntB);
        for (int s = 0; s < mcnt; s += 8) {
            int clA = max(cntA - 1, 0), clB = max(cntB - 1, 0);
            int pkA0 = __shfl(pkA_l, min(s + q, clA));
            int pkA1 = __shfl(pkA_l, min(s + 4 + q, clA));
            int pkB0 = __shfl(pkB_l, min(s + q, clB));
            int pkB1 = __shfl(pkB_l, min(s + 4 + q, clB));
            // 8 gathers issued before any use; KR and VM share one 512B row per edge
            bf16x8 krA0 = *(const bf16x8*)&KVb[(size_t)pkA0 * 256 + c * 8];
            bf16x8 krA1 = *(const bf16x8*)&KVb[(size_t)pkA1 * 256 + c * 8];
            bf16x8 krB0 = *(const bf16x8*)&KVb[(size_t)pkB0 * 256 + c * 8];
            bf16x8 krB1 = *(const bf16x8*)&KVb[(size_t)pkB1 * 256 + c * 8];
            bf16x8 vmA0 = *(const bf16x8*)&KVb[(size_t)pkA0 * 256 + 128 + c * 8];
            bf16x8 vmA1 = *(const bf16x8*)&KVb[(size_t)pkA1 * 256 + 128 + c * 8];
            bf16x8 vmB0 = *(const bf16x8*)&KVb[(size_t)pkB0 * 256 + 128 + c * 8];
            bf16x8 vmB1 = *(const bf16x8*)&KVb[(size_t)pkB1 * 256 + 128 + c * 8];

            const unsigned* ka0 = (const unsigned*)&krA0;
            const unsigned* ka1 = (const unsigned*)&krA1;
            const unsigned* kb0 = (const unsigned*)&krB0;
            const unsigned* kb1 = (const unsigned*)&krB1;
            float dA0 = 0.f, dA1 = 0.f, dB0 = 0.f, dB1 = 0.f;
            #pragma unroll
            for (int i = 0; i < 4; ++i) {
                dA0 = fmaf(QfA[2*i],   __uint_as_float(ka0[i] << 16), dA0);
                dA0 = fmaf(QfA[2*i+1], __uint_as_float(ka0[i] & 0xffff0000u), dA0);
                dA1 = fmaf(QfA[2*i],   __uint_as_float(ka1[i] << 16), dA1);
                dA1 = fmaf(QfA[2*i+1], __uint_as_float(ka1[i] & 0xffff0000u), dA1);
                dB0 = fmaf(QfB[2*i],   __uint_as_float(kb0[i] << 16), dB0);
                dB0 = fmaf(QfB[2*i+1], __uint_as_float(kb0[i] & 0xffff0000u), dB0);
                dB1 = fmaf(QfB[2*i],   __uint_as_float(kb1[i] << 16), dB1);
                dB1 = fmaf(QfB[2*i+1], __uint_as_float(kb1[i] & 0xffff0000u), dB1);
            }
            dA0 += __shfl_xor(dA0, 1);
            dA1 += __shfl_xor(dA1, 1);
            dB0 += __shfl_xor(dB0, 1);
            dB1 += __shfl_xor(dB1, 1);
            float wA0 = (s + q < cntA)     ? __expf(dA0) : 0.f;
            float wA1 = (s + 4 + q < cntA) ? __expf(dA1) : 0.f;
            float wB0 = (s + q < cntB)     ? __expf(dB0) : 0.f;
            float wB1 = (s + 4 + q < cntB) ? __expf(dB1) : 0.f;
            denA += wA0 + wA1;
            denB += wB0 + wB1;

            const unsigned* va0 = (const unsigned*)&vmA0;
            const unsigned* va1 = (const unsigned*)&vmA1;
            const unsigned* vb0 = (const unsigned*)&vmB0;
            const unsigned* vb1 = (const unsigned*)&vmB1;
            #pragma unroll
            for (int i = 0; i < 4; ++i) {
                SA[2*i]   = fmaf(wA0, __uint_as_float(va0[i] << 16), SA[2*i]);
                SA[2*i+1] = fmaf(wA0, __uint_as_float(va0[i] & 0xffff0000u), SA[2*i+1]);
                SA[2*i]   = fmaf(wA1, __uint_as_float(va1[i] << 16), SA[2*i]);
                SA[2*i+1] = fmaf(wA1, __uint_as_float(va1[i] & 0xffff0000u), SA[2*i+1]);
                SB[2*i]   = fmaf(wB0, __uint_as_float(vb0[i] << 16), SB[2*i]);
                SB[2*i+1] = fmaf(wB0, __uint_as_float(vb0[i] & 0xffff0000u), SB[2*i+1]);
                SB[2*i]   = fmaf(wB1, __uint_as_float(vb1[i] << 16), SB[2*i]);
                SB[2*i+1] = fmaf(wB1, __uint_as_float(vb1[i] & 0xffff0000u), SB[2*i+1]);
            }
        }
    }

    #pragma unroll
    for (int m = 16; m <= 32; m <<= 1) {
        denA += __shfl_xor(denA, m);
        denB += __shfl_xor(denB, m);
        #pragma unroll
        for (int i = 0; i < 8; ++i) {
            SA[i] += __shfl_xor(SA[i], m);
            SB[i] += __shfl_xor(SB[i], m);
        }
    }
    float invA = (denA > 0.f) ? 1.f / denA : 0.f;
    float invB = (denB > 0.f) ? 1.f / denB : 0.f;
    float o[8];
    #pragma unroll
    for (int i = 0; i < 8; ++i) o[i] = (q == 1) ? SB[i] * invB : SA[i] * invA;
    int sd = (q == 1) ? dstB : dstA;
    if (q == 0 || (q == 1 && hasB)) {
        *(float4*)&aggr[(size_t)sd * 128 + c * 8]     = make_float4(o[0], o[1], o[2], o[3]);
        *(float4*)&aggr[(size_t)sd * 128 + c * 8 + 4] = make_float4(o[4], o[5], o[6], o[7]);
    }
}

// ---------------- MFMA gelu + Wa proj + skip + LayerNorm (transposed D, aggr aliases d_out) ----------------
__global__ __launch_bounds__(256)
void node_out_mfma(const float* __restrict__ aggr, const float* __restrict__ x,
                   const int* __restrict__ order_p, const int* __restrict__ pad_off,
                   const unsigned short* __restrict__ Wat, const float* __restrict__ ba,
                   const float* __restrict__ skip, const float* __restrict__ gamma,
                   const float* __restrict__ beta, float* __restrict__ out, int N) {
    __shared__ unsigned hsm[64 * 64];
    __shared__ int gid_s[64];
    int tid = threadIdx.x;
    int base = blockIdx.x * 64;
    int t = (base >= pad_off[1]) + (base >= pad_off[2]) + (base >= pad_off[3]);

    if (tid < 64) gid_s[tid] = order_p[base + tid];
    __syncthreads();

    {
        int row = tid >> 2, q = tid & 3;
        int g = gid_s[row];
        const float4* ar = (const float4*)(aggr + (size_t)(g < 0 ? 0 : g) * 128 + q * 32);
        int swz = (row & 7) << 4;
        #pragma unroll
        for (int v4 = 0; v4 < 8; ++v4) {
            float4 f = (g >= 0) ? ar[v4] : make_float4(0.f, 0.f, 0.f, 0.f);
            float g0 = 0.5f * f.x * (1.f + erff(f.x * 0.70710678118654752f));
            float g1 = 0.5f * f.y * (1.f + erff(f.y * 0.70710678118654752f));
            float g2 = 0.5f * f.z * (1.f + erff(f.z * 0.70710678118654752f));
            float g3 = 0.5f * f.w * (1.f + erff(f.w * 0.70710678118654752f));
            unsigned ua = (unsigned)f2bf(g0) | ((unsigned)f2bf(g1) << 16);
            unsigned ub = (unsigned)f2bf(g2) | ((unsigned)f2bf(g3) << 16);
            int c2 = (q * 16 + v4 * 2) * 4;
            hsm[(row << 6) + (((c2) ^ swz) >> 2)] = ua;
            hsm[(row << 6) + (((c2 + 4) ^ swz) >> 2)] = ub;
        }
    }
    __syncthreads();

    int w = tid >> 6, l = tid & 63;
    int rowbase = w * 16, lr = l & 15, lg = l >> 4;
    int myrow = rowbase + lr;

    bf16x8 afr[4];
    #pragma unroll
    for (int ks = 0; ks < 4; ++ks) {
        int byteoff = (ks * 64 + lg * 16) ^ ((lr & 7) << 4);
        afr[ks] = *reinterpret_cast<const bf16x8*>(
            reinterpret_cast<const char*>(&hsm[myrow << 6]) + byteoff);
    }

    float al = 1.f / (1.f + __expf(-skip[t]));
    int g = gid_s[myrow];

    float pre[8][4];
    float s = 0.f, sq = 0.f;

    #pragma unroll
    for (int c = 0; c < 8; ++c) {
        const unsigned short* wb = Wat + ((size_t)t << 14) + (size_t)(c * 16 + lr) * 128 + lg * 8;
        f32x4 acc = {0.f, 0.f, 0.f, 0.f};
        #pragma unroll
        for (int ks = 0; ks < 4; ++ks)
            acc = __builtin_amdgcn_mfma_f32_16x16x32_bf16(
                *(const bf16x8*)(wb + ks * 32), afr[ks], acc, 0, 0, 0);
        float4 bav = *(const float4*)&ba[t * 128 + c * 16 + lg * 4];
        float4 xv = (g >= 0) ? *(const float4*)&x[(size_t)g * 128 + c * 16 + lg * 4]
                             : make_float4(0.f, 0.f, 0.f, 0.f);
        float p0 = (acc[0] + bav.x) * al + xv.x * (1.f - al);
        float p1 = (acc[1] + bav.y) * al + xv.y * (1.f - al);
        float p2 = (acc[2] + bav.z) * al + xv.z * (1.f - al);
        float p3 = (acc[3] + bav.w) * al + xv.w * (1.f - al);
        pre[c][0] = p0; pre[c][1] = p1; pre[c][2] = p2; pre[c][3] = p3;
        s += p0 + p1 + p2 + p3;
        sq += p0 * p0 + p1 * p1 + p2 * p2 + p3 * p3;
    }

    s  += __shfl_xor(s, 16);  sq += __shfl_xor(sq, 16);
    s  += __shfl_xor(s, 32);  sq += __shfl_xor(sq, 32);
    float mu = s * (1.f / 128.f);
    float var = sq * (1.f / 128.f) - mu * mu;
    float rs = rsqrtf(fmaxf(var, 0.f) + 1e-5f);

    #pragma unroll
    for (int c = 0; c < 8; ++c) {
        float4 ga = *(const float4*)&gamma[t * 128 + c * 16 + lg * 4];
        float4 be = *(const float4*)&beta[t * 128 + c * 16 + lg * 4];
        float4 o;
        o.x = (pre[c][0] - mu) * rs * ga.x + be.x;
        o.y = (pre[c][1] - mu) * rs * ga.y + be.y;
        o.z = (pre[c][2] - mu) * rs * ga.z + be.z;
        o.w = (pre[c][3] - mu) * rs * ga.w + be.w;
        if (g >= 0) *(float4*)&out[(size_t)g * 128 + c * 16 + lg * 4] = o;
    }
}

extern "C" void kernel_launch(void* const* d_in, const int* in_sizes, int n_in,
                              void* d_out, int out_size, void* d_ws, size_t ws_size,
                              hipStream_t stream) {
    const float* x   = (const float*)d_in[0];
    const int*   nt  = (const int*)d_in[1];
    const int*   ei  = (const int*)d_in[2];
    const int*   et  = (const int*)d_in[3];
    const float* Wk = (const float*)d_in[5];  const float* bk = (const float*)d_in[6];
    const float* Wq = (const float*)d_in[7];  const float* bq = (const float*)d_in[8];
    const float* Wv = (const float*)d_in[9];  const float* bv = (const float*)d_in[10];
    const float* Wa = (const float*)d_in[11]; const float* ba = (const float*)d_in[12];
    const float* rel_pri = (const float*)d_in[13];
    const float* rel_att = (const float*)d_in[14];
    const float* rel_msg = (const float*)d_in[15];
    const float* skip    = (const float*)d_in[16];
    const float* gamma   = (const float*)d_in[17];
    const float* beta    = (const float*)d_in[18];

    const int N = in_sizes[0] / 128;
    const int E = in_sizes[3];
    const int NB = (N + 511) / 512;
    const int NB256 = (N + 255) / 256;

    unsigned short* Qb  = (unsigned short*)d_ws;           // N*128 bf16
    unsigned short* KVb = Qb + (size_t)N * 128;            // N*4 rows x 256 shorts (KR|VM)
    unsigned short* Wqt = KVb + (size_t)N * 1024;          // 65536
    unsigned short* Wat = Wqt + 65536;                     // 65536
    unsigned short* Wkrt = Wat + 65536;                    // 262144
    unsigned short* Wvmt = Wkrt + 262144;                  // 262144
    float* bkr = (float*)(Wvmt + 262144);                  // 2048
    float* bvm = bkr + 2048;                               // 2048
    int* order_p = (int*)(bvm + 2048);                     // N+320
    int* blockcnt = order_p + N + 320;                     // NB256*4
    int* boff     = blockcnt + NB256 * 4;                  // NB256*4
    int* pad_off  = boff + NB256 * 4;                      // 8
    int* deg     = pad_off + 8;                            // N  (deg, cursorD adjacent: one memset)
    int* cursorD = deg + N;                                // N
    int* off     = cursorD + N;                            // N
    int* bsum    = off + N;                                // NB+8
    int* elist   = bsum + NB + 8;                          // E
    float* aggr  = (float*)d_out;                          // aliases output (safe: see node_out)

    hipMemsetAsync(deg, 0, (size_t)(2 * N) * sizeof(int), stream);

    count_types_k<<<NB256, 256, 0, stream>>>(nt, blockcnt, N);
    scan_blocks_k<<<1, 256, 0, stream>>>(blockcnt, NB256, N, boff, pad_off, order_p);
    scatter_types_k<<<NB256, 256, 0, stream>>>(nt, boff, order_p, N);

    prep_weights_k<<<1024, 256, 0, stream>>>(Wk, Wq, Wv, Wa, bk, bv, rel_att, rel_msg,
                                             rel_pri, Wqt, Wat, Wkrt, Wvmt, bkr, bvm);

    deg_k<<<(E + 255) / 256, 256, 0, stream>>>(ei, deg, E);
    scan1_k<<<NB, 512, 0, stream>>>(deg, off, bsum, N);
    scan23_k<<<NB, 512, 0, stream>>>(off, bsum, N);
    scatter_edges_k<<<(E + 255) / 256, 256, 0, stream>>>(ei, et, off, cursorD, elist, E);

    int nb64 = (N + 252 + 63) / 64;
    proj_mfma<<<nb64, 256, 0, stream>>>(x, order_p, pad_off, Wqt, bq, Wkrt, bkr, Wvmt, bvm,
                                        Qb, KVb, N);
    int npairs = (N + 1) / 2;
    edge_fused<<<(npairs + 3) / 4, 256, 0, stream>>>(Qb, KVb, off, elist, aggr, N, E);
    node_out_mfma<<<nb64, 256, 0, stream>>>(aggr, x, order_p, pad_off, Wat, ba, skip,
                                            gamma, beta, (float*)d_out, N);
}

// Round 15
// 379.967 us; speedup vs baseline: 1.1128x; 1.0325x over previous
//
#include <hip/hip_runtime.h>
#include <math.h>

#define D_DIM 128

using bf16x8 = __attribute__((ext_vector_type(8))) short;
using f32x4  = __attribute__((ext_vector_type(4))) float;

__device__ __forceinline__ unsigned short f2bf(float f) {
    unsigned u = __float_as_uint(f);
    u += 0x7fffu + ((u >> 16) & 1u);   // RNE
    return (unsigned short)(u >> 16);
}

// ---------------- type sort: ballot-based stable partition (no global atomics) ----------------
__global__ __launch_bounds__(256)
void count_types_k(const int* __restrict__ nt, int* __restrict__ blockcnt, int N) {
    __shared__ int wcnt[4][4];
    int tid = threadIdx.x;
    int i = blockIdx.x * 256 + tid;
    int w = tid >> 6, l = tid & 63;
    int t = (i < N) ? nt[i] : -1;
    #pragma unroll
    for (int tt = 0; tt < 4; ++tt) {
        unsigned long long m = __ballot(t == tt);
        if (l == 0) wcnt[w][tt] = __popcll(m);
    }
    __syncthreads();
    if (tid < 4) {
        blockcnt[blockIdx.x * 4 + tid] =
            wcnt[0][tid] + wcnt[1][tid] + wcnt[2][tid] + wcnt[3][tid];
    }
}

__global__ __launch_bounds__(256)
void scan_blocks_k(const int* __restrict__ blockcnt, int nb, int N,
                   int* __restrict__ boff, int* __restrict__ pad_off,
                   int* __restrict__ order_p) {
    __shared__ int tot_s[4];
    __shared__ int po_s[5];
    int tid = threadIdx.x;
    int t = tid >> 6, l = tid & 63;
    int sum = 0;
    for (int base = 0; base < nb; base += 64) {
        int b = base + l;
        sum += (b < nb) ? blockcnt[b * 4 + t] : 0;
    }
    #pragma unroll
    for (int m = 1; m < 64; m <<= 1) sum += __shfl_xor(sum, m);
    if (l == 0) tot_s[t] = sum;
    __syncthreads();
    if (tid == 0) {
        int s = 0;
        for (int tt = 0; tt < 4; ++tt) { po_s[tt] = s; s += ((tot_s[tt] + 63) >> 6) << 6; }
        po_s[4] = s;
        for (int tt = 0; tt < 5; ++tt) pad_off[tt] = po_s[tt];
    }
    __syncthreads();
    // fill pad slots with -1 (bounded by allocation N+320 — round-10 overflow lesson)
    #pragma unroll 1
    for (int tt = 0; tt < 4; ++tt) {
        int gs = po_s[tt] + tot_s[tt], ge = po_s[tt + 1];
        for (int i = gs + tid; i < ge; i += 256) order_p[i] = -1;
    }
    for (int i = po_s[4] + tid; i < N + 320; i += 256) order_p[i] = -1;
    __syncthreads();
    int run = po_s[t];
    for (int base = 0; base < nb; base += 64) {
        int b = base + l;
        int v = (b < nb) ? blockcnt[b * 4 + t] : 0;
        int incl = v;
        #pragma unroll
        for (int off = 1; off < 64; off <<= 1) {
            int up = __shfl_up(incl, off);
            if (l >= off) incl += up;
        }
        if (b < nb) boff[b * 4 + t] = run + incl - v;
        run += __shfl(incl, 63);
    }
}

__global__ __launch_bounds__(256)
void scatter_types_k(const int* __restrict__ nt, const int* __restrict__ boff,
                     int* __restrict__ order_p, int N) {
    __shared__ int wbase[4][4];
    int tid = threadIdx.x;
    int i = blockIdx.x * 256 + tid;
    int w = tid >> 6, l = tid & 63;
    int t = (i < N) ? nt[i] : -1;
    int rank = 0;
    #pragma unroll
    for (int tt = 0; tt < 4; ++tt) {
        unsigned long long m = __ballot(t == tt);
        if (l == 0) wbase[w][tt] = __popcll(m);
        if (t == tt) rank = __popcll(m & ((1ull << l) - 1ull));
    }
    __syncthreads();
    if (tid < 4) {
        int run = 0;
        for (int ww = 0; ww < 4; ++ww) { int c = wbase[ww][tid]; wbase[ww][tid] = run; run += c; }
    }
    __syncthreads();
    if (i < N) order_p[boff[blockIdx.x * 4 + t] + wbase[w][t] + rank] = i;
}

// ---------------- fused weight prep ----------------
__global__ __launch_bounds__(256)
void prep_weights_k(const float* __restrict__ Wk, const float* __restrict__ Wq,
                    const float* __restrict__ Wv, const float* __restrict__ Wa,
                    const float* __restrict__ bk, const float* __restrict__ bv,
                    const float* __restrict__ rel_att, const float* __restrict__ rel_msg,
                    const float* __restrict__ rel_pri,
                    unsigned short* __restrict__ Wqt, unsigned short* __restrict__ Wat,
                    unsigned short* __restrict__ Wkrt, unsigned short* __restrict__ Wvmt,
                    float* __restrict__ bkr, float* __restrict__ bvm) {
    int idx = blockIdx.x * 256 + threadIdx.x;  // 262144 = 16*128*128
    int i = idx & 127;
    int col = (idx >> 7) & 127;
    int r = (idx >> 14) & 3;
    int t = idx >> 16;
    int h = col >> 4, k = col & 15;
    {
        const float* wk = Wk + t * 16384 + i * 128 + h * 16;
        const float* wv = Wv + t * 16384 + i * 128 + h * 16;
        const float* ra = rel_att + ((r * 8 + h) * 16) * 16 + k;
        const float* rm = rel_msg + ((r * 8 + h) * 16) * 16 + k;
        float s1 = 0.f, s2 = 0.f;
        #pragma unroll
        for (int d = 0; d < 16; ++d) {
            s1 += wk[d] * ra[d * 16];
            s2 += wv[d] * rm[d * 16];
        }
        Wkrt[idx] = f2bf(s1 * rel_pri[r * 8 + h] * 0.25f);
        Wvmt[idx] = f2bf(s2);
    }
    if (idx < 65536) {
        int t2 = idx >> 14, rem = idx & 16383, row = rem >> 7, col2 = rem & 127;
        int d = (t2 << 14) | (col2 << 7) | row;
        Wqt[d] = f2bf(Wq[idx]);
        Wat[d] = f2bf(Wa[idx]);
    }
    if (idx < 4096) {
        int bi = idx & 2047;
        int col3 = bi & 127, r3 = (bi >> 7) & 3, t3 = bi >> 9;
        int h3 = col3 >> 4, k3 = col3 & 15;
        float s = 0.f;
        if (idx < 2048) {
            #pragma unroll
            for (int d = 0; d < 16; ++d)
                s += bk[t3 * 128 + h3 * 16 + d] * rel_att[((r3 * 8 + h3) * 16 + d) * 16 + k3];
            bkr[bi] = s * rel_pri[r3 * 8 + h3] * 0.25f;
        } else {
            #pragma unroll
            for (int d = 0; d < 16; ++d)
                s += bv[t3 * 128 + h3 * 16 + d] * rel_msg[((r3 * 8 + h3) * 16 + d) * 16 + k3];
            bvm[bi] = s;
        }
    }
}

// ---------------- dst-CSR build ----------------
__global__ void deg_k(const int* __restrict__ ei, int* __restrict__ deg, int E) {
    int e = blockIdx.x * 256 + threadIdx.x;
    if (e < E) atomicAdd(&deg[ei[E + e]], 1);
}
__global__ void scan1_k(const int* __restrict__ deg, int* __restrict__ excl,
                        int* __restrict__ bsum, int N) {
    __shared__ int s[512];
    int i = blockIdx.x * 512 + threadIdx.x;
    int v = (i < N) ? deg[i] : 0;
    s[threadIdx.x] = v;
    __syncthreads();
    for (int off = 1; off < 512; off <<= 1) {
        int t = (threadIdx.x >= off) ? s[threadIdx.x - off] : 0;
        __syncthreads();
        s[threadIdx.x] += t;
        __syncthreads();
    }
    if (i < N) excl[i] = s[threadIdx.x] - v;
    if (threadIdx.x == 511) bsum[blockIdx.x] = s[511];
}
// fused scan2+scan3
__global__ void scan23_k(int* __restrict__ excl, const int* __restrict__ bsum, int N) {
    __shared__ int pre_s;
    int b = blockIdx.x;
    int tid = threadIdx.x, l = tid & 63;
    if (tid < 64) {
        int sum = 0;
        for (int j = l; j < b; j += 64) sum += bsum[j];
        #pragma unroll
        for (int m = 1; m < 64; m <<= 1) sum += __shfl_xor(sum, m);
        if (l == 0) pre_s = sum;
    }
    __syncthreads();
    int i = b * 512 + tid;
    if (i < N) excl[i] += pre_s;
}
__global__ void scatter_edges_k(const int* __restrict__ ei, const int* __restrict__ et,
                                const int* __restrict__ off, int* __restrict__ cursor,
                                int* __restrict__ elist, int E) {
    int e = blockIdx.x * 256 + threadIdx.x;
    if (e < E) {
        int dst = ei[E + e];
        int p = off[dst] + atomicAdd(&cursor[dst], 1);
        elist[p] = (ei[e] << 2) | et[e];
    }
}

// ---------------- MFMA projection (weight-shared): Q + interleaved KR/VM rows ----------------
// KVb row pk = g*4 + r (256 shorts): [0:128]=KR[r], [128:256]=VM[r]
__global__ __launch_bounds__(256, 4)
void proj_mfma(const float* __restrict__ x, const int* __restrict__ order_p,
               const int* __restrict__ pad_off,
               const unsigned short* __restrict__ Wqt, const float* __restrict__ bq,
               const unsigned short* __restrict__ W_kr_t, const float* __restrict__ bkr,
               const unsigned short* __restrict__ W_vm_t, const float* __restrict__ bvm,
               unsigned short* __restrict__ Qb, unsigned short* __restrict__ KVb, int N) {
    __shared__ unsigned shmem[64 * 128];
    __shared__ int gid_s[64];
    unsigned* xs = shmem;
    char* stageb = (char*)shmem;
    int tid = threadIdx.x;
    int base = blockIdx.x * 64;
    int t = (base >= pad_off[1]) + (base >= pad_off[2]) + (base >= pad_off[3]);

    if (tid < 64) gid_s[tid] = order_p[base + tid];
    __syncthreads();

    {   // stage x -> bf16 swizzled LDS
        int row = tid >> 2, q = tid & 3;
        int g = gid_s[row];
        const float4* xr = (const float4*)(x + (size_t)(g < 0 ? 0 : g) * 128 + q * 32);
        int swz = (row & 7) << 4;
        #pragma unroll
        for (int v4 = 0; v4 < 8; ++v4) {
            float4 f = (g >= 0) ? xr[v4] : make_float4(0.f, 0.f, 0.f, 0.f);
            unsigned ua = (unsigned)f2bf(f.x) | ((unsigned)f2bf(f.y) << 16);
            unsigned ub = (unsigned)f2bf(f.z) | ((unsigned)f2bf(f.w) << 16);
            int c2 = (q * 16 + v4 * 2) * 4;
            xs[(row << 6) + (((c2) ^ swz) >> 2)] = ua;
            xs[(row << 6) + (((c2 + 4) ^ swz) >> 2)] = ub;
        }
    }
    __syncthreads();

    int w = tid >> 6, l = tid & 63;
    int lr = l & 15, lg = l >> 4;

    bf16x8 afr[4][4];
    #pragma unroll
    for (int j = 0; j < 4; ++j) {
        int row = j * 16 + lr;
        #pragma unroll
        for (int ks = 0; ks < 4; ++ks) {
            int byteoff = (ks * 64 + lg * 16) ^ ((lr & 7) << 4);
            afr[j][ks] = *reinterpret_cast<const bf16x8*>(
                reinterpret_cast<const char*>(&xs[row << 6]) + byteoff);
        }
    }
    __syncthreads();

    #pragma unroll 1
    for (int pass = 0; pass < 4; ++pass) {
        bool isKR = (pass < 2);
        int m0 = (pass & 1) * 2;
        const unsigned short* Wp = (isKR ? W_kr_t : W_vm_t) + ((size_t)(t * 4 + m0) << 14);
        const float* bp = (isKR ? bkr : bvm) + (t * 4 + m0) * 128;

        #pragma unroll
        for (int ci = 0; ci < 2; ++ci) {
            int c = w * 2 + ci;
            #pragma unroll
            for (int mm = 0; mm < 2; ++mm) {
                const unsigned short* wb = Wp + ((size_t)mm << 14)
                                         + (size_t)(c * 16 + lr) * 128 + lg * 8;
                bf16x8 wfr[4];
                #pragma unroll
                for (int ks = 0; ks < 4; ++ks) wfr[ks] = *(const bf16x8*)(wb + ks * 32);
                f32x4 acc0 = {0.f,0.f,0.f,0.f}, acc1 = {0.f,0.f,0.f,0.f};
                f32x4 acc2 = {0.f,0.f,0.f,0.f}, acc3 = {0.f,0.f,0.f,0.f};
                #pragma unroll
                for (int ks = 0; ks < 4; ++ks) {
                    acc0 = __builtin_amdgcn_mfma_f32_16x16x32_bf16(wfr[ks], afr[0][ks], acc0, 0, 0, 0);
                    acc1 = __builtin_amdgcn_mfma_f32_16x16x32_bf16(wfr[ks], afr[1][ks], acc1, 0, 0, 0);
                    acc2 = __builtin_amdgcn_mfma_f32_16x16x32_bf16(wfr[ks], afr[2][ks], acc2, 0, 0, 0);
                    acc3 = __builtin_amdgcn_mfma_f32_16x16x32_bf16(wfr[ks], afr[3][ks], acc3, 0, 0, 0);
                }
                float4 bb = *(const float4*)&bp[mm * 128 + c * 16 + lg * 4];
                int colb = (mm * 128 + c * 16 + lg * 4) * 2;
                f32x4 accs[4] = {acc0, acc1, acc2, acc3};
                #pragma unroll
                for (int j = 0; j < 4; ++j) {
                    int node = j * 16 + lr;
                    unsigned p0 = (unsigned)f2bf(accs[j][0] + bb.x) | ((unsigned)f2bf(accs[j][1] + bb.y) << 16);
                    unsigned p1 = (unsigned)f2bf(accs[j][2] + bb.z) | ((unsigned)f2bf(accs[j][3] + bb.w) << 16);
                    int byte = (node * 512 + colb) ^ ((node & 7) << 4);
                    *(uint2*)(stageb + byte) = make_uint2(p0, p1);
                }
            }
        }
        __syncthreads();
        #pragma unroll
        for (int i = 0; i < 8; ++i) {
            int row = w * 16 + i * 2 + (l >> 5);
            int l32 = l & 31;
            int byte = (row * 512 + l32 * 16) ^ ((row & 7) << 4);
            uint4 v = *(const uint4*)(stageb + byte);
            int g = gid_s[row];
            if (g >= 0) {
                int mat = m0 + (l32 >> 4);
                int coloff = (l32 & 15) * 8 + (isKR ? 0 : 128);
                *(uint4*)&KVb[((size_t)g * 4 + mat) * 256 + coloff] = v;
            }
        }
        __syncthreads();
    }

    // ---- Q pass ----
    #pragma unroll
    for (int ci = 0; ci < 2; ++ci) {
        int c = w * 2 + ci;
        const unsigned short* wb = Wqt + ((size_t)t << 14) + (size_t)(c * 16 + lr) * 128 + lg * 8;
        bf16x8 wfr[4];
        #pragma unroll
        for (int ks = 0; ks < 4; ++ks) wfr[ks] = *(const bf16x8*)(wb + ks * 32);
        f32x4 acc0 = {0.f,0.f,0.f,0.f}, acc1 = {0.f,0.f,0.f,0.f};
        f32x4 acc2 = {0.f,0.f,0.f,0.f}, acc3 = {0.f,0.f,0.f,0.f};
        #pragma unroll
        for (int ks = 0; ks < 4; ++ks) {
            acc0 = __builtin_amdgcn_mfma_f32_16x16x32_bf16(wfr[ks], afr[0][ks], acc0, 0, 0, 0);
            acc1 = __builtin_amdgcn_mfma_f32_16x16x32_bf16(wfr[ks], afr[1][ks], acc1, 0, 0, 0);
            acc2 = __builtin_amdgcn_mfma_f32_16x16x32_bf16(wfr[ks], afr[2][ks], acc2, 0, 0, 0);
            acc3 = __builtin_amdgcn_mfma_f32_16x16x32_bf16(wfr[ks], afr[3][ks], acc3, 0, 0, 0);
        }
        float4 bb = *(const float4*)&bq[t * 128 + c * 16 + lg * 4];
        int colb = (c * 16 + lg * 4) * 2;
        f32x4 accs[4] = {acc0, acc1, acc2, acc3};
        #pragma unroll
        for (int j = 0; j < 4; ++j) {
            int node = j * 16 + lr;
            unsigned p0 = (unsigned)f2bf(accs[j][0] + bb.x) | ((unsigned)f2bf(accs[j][1] + bb.y) << 16);
            unsigned p1 = (unsigned)f2bf(accs[j][2] + bb.z) | ((unsigned)f2bf(accs[j][3] + bb.w) << 16);
            int byte = (node * 256 + colb) ^ ((node & 7) << 4);
            *(uint2*)(stageb + byte) = make_uint2(p0, p1);
        }
    }
    __syncthreads();
    #pragma unroll
    for (int i = 0; i < 4; ++i) {
        int row = w * 16 + i * 4 + (l >> 4);
        int l16 = l & 15;
        int byte = (row * 256 + l16 * 16) ^ ((row & 7) << 4);
        uint4 v = *(const uint4*)(stageb + byte);
        int g = gid_s[row];
        if (g >= 0) *(uint4*)&Qb[(size_t)g * 128 + l16 * 8] = v;
    }
}

// ---------------- edge kernel: 4 dsts per wave, cross-dst software pipeline ----------------
// lane l: quarter q=l>>4 (edge slot), chunk c=l&15 (dims 8c..8c+7)
__global__ __launch_bounds__(256)
void edge_fused(const unsigned short* __restrict__ Qb,
                const unsigned short* __restrict__ KVb,
                const int* __restrict__ off, const int* __restrict__ elist,
                float* __restrict__ aggr, int N, int E) {
    int w = threadIdx.x >> 6, l = threadIdx.x & 63;
    int d0 = (blockIdx.x * 4 + w) * 4;   // 4 consecutive dsts per wave
    if (d0 >= N) return;
    int q = l >> 4, c = l & 15;

    // load 5 CSR offsets in one shot (lanes 0..4), broadcast
    int oe = E;
    if (l < 5) {
        int d = d0 + l;
        if (d < N) oe = off[d];
    }
    int e_b[5];
    #pragma unroll
    for (int i = 0; i < 5; ++i) e_b[i] = __shfl(oe, i);

    // prefetch dst0's elist + Q
    int deg0 = e_b[1] - e_b[0];
    int pk_cur = (deg0 > 0) ? elist[e_b[0] + min(l, deg0 - 1)] : 0;
    bf16x8 q_cur = *(const bf16x8*)&Qb[(size_t)d0 * 128 + c * 8];

    #pragma unroll 1
    for (int j = 0; j < 4; ++j) {
        int dst = d0 + j;
        if (dst >= N) break;
        int e0 = e_b[j];
        int deg = e_b[j + 1] - e0;

        // issue next dst's elist + Q loads BEFORE touching current data
        int pk_nxt = 0;
        bf16x8 q_nxt = q_cur;
        if (j < 3 && dst + 1 < N) {
            int dn = e_b[j + 2] - e_b[j + 1];
            if (dn > 0) pk_nxt = elist[e_b[j + 1] + min(l, dn - 1)];
            q_nxt = *(const bf16x8*)&Qb[(size_t)(dst + 1) * 128 + c * 8];
        }

        float Qf[8];
        {
            const unsigned* qu = (const unsigned*)&q_cur;
            #pragma unroll
            for (int i = 0; i < 4; ++i) {
                Qf[2*i]   = __uint_as_float(qu[i] << 16);
                Qf[2*i+1] = __uint_as_float(qu[i] & 0xffff0000u);
            }
        }

        float S[8] = {0.f,0.f,0.f,0.f,0.f,0.f,0.f,0.f};
        float den = 0.f;
        int pk_l = pk_cur;

        for (int base = 0; base < deg; base += 64) {
            if (base > 0) pk_l = elist[e0 + min(base + l, deg - 1)];
            int cnt = min(64, deg - base);
            for (int s = 0; s < cnt; s += 8) {
                int cl = cnt - 1;
                int pk0 = __shfl(pk_l, min(s + q, cl));
                int pk1 = __shfl(pk_l, min(s + 4 + q, cl));
                // 4 gathers issued before any use; KR|VM share one 512B row
                bf16x8 kr0 = *(const bf16x8*)&KVb[(size_t)pk0 * 256 + c * 8];
                bf16x8 kr1 = *(const bf16x8*)&KVb[(size_t)pk1 * 256 + c * 8];
                bf16x8 vm0 = *(const bf16x8*)&KVb[(size_t)pk0 * 256 + 128 + c * 8];
                bf16x8 vm1 = *(const bf16x8*)&KVb[(size_t)pk1 * 256 + 128 + c * 8];

                const unsigned* k0 = (const unsigned*)&kr0;
                const unsigned* k1 = (const unsigned*)&kr1;
                float dt0 = 0.f, dt1 = 0.f;
                #pragma unroll
                for (int i = 0; i < 4; ++i) {
                    dt0 = fmaf(Qf[2*i],   __uint_as_float(k0[i] << 16), dt0);
                    dt0 = fmaf(Qf[2*i+1], __uint_as_float(k0[i] & 0xffff0000u), dt0);
                    dt1 = fmaf(Qf[2*i],   __uint_as_float(k1[i] << 16), dt1);
                    dt1 = fmaf(Qf[2*i+1], __uint_as_float(k1[i] & 0xffff0000u), dt1);
                }
                dt0 += __shfl_xor(dt0, 1);
                dt1 += __shfl_xor(dt1, 1);
                float w0 = (s + q < cnt)     ? __expf(dt0) : 0.f;
                float w1 = (s + 4 + q < cnt) ? __expf(dt1) : 0.f;
                den += w0 + w1;

                const unsigned* v0 = (const unsigned*)&vm0;
                const unsigned* v1 = (const unsigned*)&vm1;
                #pragma unroll
                for (int i = 0; i < 4; ++i) {
                    S[2*i]   = fmaf(w0, __uint_as_float(v0[i] << 16), S[2*i]);
                    S[2*i+1] = fmaf(w0, __uint_as_float(v0[i] & 0xffff0000u), S[2*i+1]);
                    S[2*i]   = fmaf(w1, __uint_as_float(v1[i] << 16), S[2*i]);
                    S[2*i+1] = fmaf(w1, __uint_as_float(v1[i] & 0xffff0000u), S[2*i+1]);
                }
            }
        }

        // reduce across quarters, store
        #pragma unroll
        for (int m = 16; m <= 32; m <<= 1) {
            den += __shfl_xor(den, m);
            #pragma unroll
            for (int i = 0; i < 8; ++i) S[i] += __shfl_xor(S[i], m);
        }
        if (q == 0) {
            float inv = (den > 0.f) ? 1.f / den : 0.f;
            *(float4*)&aggr[(size_t)dst * 128 + c * 8] =
                make_float4(S[0]*inv, S[1]*inv, S[2]*inv, S[3]*inv);
            *(float4*)&aggr[(size_t)dst * 128 + c * 8 + 4] =
                make_float4(S[4]*inv, S[5]*inv, S[6]*inv, S[7]*inv);
        }
        pk_cur = pk_nxt;
        q_cur = q_nxt;
    }
}

// ---------------- MFMA gelu + Wa proj + skip + LayerNorm (transposed D, aggr aliases d_out) ----------------
__global__ __launch_bounds__(256)
void node_out_mfma(const float* __restrict__ aggr, const float* __restrict__ x,
                   const int* __restrict__ order_p, const int* __restrict__ pad_off,
                   const unsigned short* __restrict__ Wat, const float* __restrict__ ba,
                   const float* __restrict__ skip, const float* __restrict__ gamma,
                   const float* __restrict__ beta, float* __restrict__ out, int N) {
    __shared__ unsigned hsm[64 * 64];
    __shared__ int gid_s[64];
    int tid = threadIdx.x;
    int base = blockIdx.x * 64;
    int t = (base >= pad_off[1]) + (base >= pad_off[2]) + (base >= pad_off[3]);

    if (tid < 64) gid_s[tid] = order_p[base + tid];
    __syncthreads();

    {
        int row = tid >> 2, q = tid & 3;
        int g = gid_s[row];
        const float4* ar = (const float4*)(aggr + (size_t)(g < 0 ? 0 : g) * 128 + q * 32);
        int swz = (row & 7) << 4;
        #pragma unroll
        for (int v4 = 0; v4 < 8; ++v4) {
            float4 f = (g >= 0) ? ar[v4] : make_float4(0.f, 0.f, 0.f, 0.f);
            float g0 = 0.5f * f.x * (1.f + erff(f.x * 0.70710678118654752f));
            float g1 = 0.5f * f.y * (1.f + erff(f.y * 0.70710678118654752f));
            float g2 = 0.5f * f.z * (1.f + erff(f.z * 0.70710678118654752f));
            float g3 = 0.5f * f.w * (1.f + erff(f.w * 0.70710678118654752f));
            unsigned ua = (unsigned)f2bf(g0) | ((unsigned)f2bf(g1) << 16);
            unsigned ub = (unsigned)f2bf(g2) | ((unsigned)f2bf(g3) << 16);
            int c2 = (q * 16 + v4 * 2) * 4;
            hsm[(row << 6) + (((c2) ^ swz) >> 2)] = ua;
            hsm[(row << 6) + (((c2 + 4) ^ swz) >> 2)] = ub;
        }
    }
    __syncthreads();

    int w = tid >> 6, l = tid & 63;
    int rowbase = w * 16, lr = l & 15, lg = l >> 4;
    int myrow = rowbase + lr;

    bf16x8 afr[4];
    #pragma unroll
    for (int ks = 0; ks < 4; ++ks) {
        int byteoff = (ks * 64 + lg * 16) ^ ((lr & 7) << 4);
        afr[ks] = *reinterpret_cast<const bf16x8*>(
            reinterpret_cast<const char*>(&hsm[myrow << 6]) + byteoff);
    }

    float al = 1.f / (1.f + __expf(-skip[t]));
    int g = gid_s[myrow];

    float pre[8][4];
    float s = 0.f, sq = 0.f;

    #pragma unroll
    for (int c = 0; c < 8; ++c) {
        const unsigned short* wb = Wat + ((size_t)t << 14) + (size_t)(c * 16 + lr) * 128 + lg * 8;
        f32x4 acc = {0.f, 0.f, 0.f, 0.f};
        #pragma unroll
        for (int ks = 0; ks < 4; ++ks)
            acc = __builtin_amdgcn_mfma_f32_16x16x32_bf16(
                *(const bf16x8*)(wb + ks * 32), afr[ks], acc, 0, 0, 0);
        float4 bav = *(const float4*)&ba[t * 128 + c * 16 + lg * 4];
        float4 xv = (g >= 0) ? *(const float4*)&x[(size_t)g * 128 + c * 16 + lg * 4]
                             : make_float4(0.f, 0.f, 0.f, 0.f);
        float p0 = (acc[0] + bav.x) * al + xv.x * (1.f - al);
        float p1 = (acc[1] + bav.y) * al + xv.y * (1.f - al);
        float p2 = (acc[2] + bav.z) * al + xv.z * (1.f - al);
        float p3 = (acc[3] + bav.w) * al + xv.w * (1.f - al);
        pre[c][0] = p0; pre[c][1] = p1; pre[c][2] = p2; pre[c][3] = p3;
        s += p0 + p1 + p2 + p3;
        sq += p0 * p0 + p1 * p1 + p2 * p2 + p3 * p3;
    }

    s  += __shfl_xor(s, 16);  sq += __shfl_xor(sq, 16);
    s  += __shfl_xor(s, 32);  sq += __shfl_xor(sq, 32);
    float mu = s * (1.f / 128.f);
    float var = sq * (1.f / 128.f) - mu * mu;
    float rs = rsqrtf(fmaxf(var, 0.f) + 1e-5f);

    #pragma unroll
    for (int c = 0; c < 8; ++c) {
        float4 ga = *(const float4*)&gamma[t * 128 + c * 16 + lg * 4];
        float4 be = *(const float4*)&beta[t * 128 + c * 16 + lg * 4];
        float4 o;
        o.x = (pre[c][0] - mu) * rs * ga.x + be.x;
        o.y = (pre[c][1] - mu) * rs * ga.y + be.y;
        o.z = (pre[c][2] - mu) * rs * ga.z + be.z;
        o.w = (pre[c][3] - mu) * rs * ga.w + be.w;
        if (g >= 0) *(float4*)&out[(size_t)g * 128 + c * 16 + lg * 4] = o;
    }
}

extern "C" void kernel_launch(void* const* d_in, const int* in_sizes, int n_in,
                              void* d_out, int out_size, void* d_ws, size_t ws_size,
                              hipStream_t stream) {
    const float* x   = (const float*)d_in[0];
    const int*   nt  = (const int*)d_in[1];
    const int*   ei  = (const int*)d_in[2];
    const int*   et  = (const int*)d_in[3];
    const float* Wk = (const float*)d_in[5];  const float* bk = (const float*)d_in[6];
    const float* Wq = (const float*)d_in[7];  const float* bq = (const float*)d_in[8];
    const float* Wv = (const float*)d_in[9];  const float* bv = (const float*)d_in[10];
    const float* Wa = (const float*)d_in[11]; const float* ba = (const float*)d_in[12];
    const float* rel_pri = (const float*)d_in[13];
    const float* rel_att = (const float*)d_in[14];
    const float* rel_msg = (const float*)d_in[15];
    const float* skip    = (const float*)d_in[16];
    const float* gamma   = (const float*)d_in[17];
    const float* beta    = (const float*)d_in[18];

    const int N = in_sizes[0] / 128;
    const int E = in_sizes[3];
    const int NB = (N + 511) / 512;
    const int NB256 = (N + 255) / 256;

    unsigned short* Qb  = (unsigned short*)d_ws;           // N*128 bf16
    unsigned short* KVb = Qb + (size_t)N * 128;            // N*4 rows x 256 shorts (KR|VM)
    unsigned short* Wqt = KVb + (size_t)N * 1024;          // 65536
    unsigned short* Wat = Wqt + 65536;                     // 65536
    unsigned short* Wkrt = Wat + 65536;                    // 262144
    unsigned short* Wvmt = Wkrt + 262144;                  // 262144
    float* bkr = (float*)(Wvmt + 262144);                  // 2048
    float* bvm = bkr + 2048;                               // 2048
    int* order_p = (int*)(bvm + 2048);                     // N+320
    int* blockcnt = order_p + N + 320;                     // NB256*4
    int* boff     = blockcnt + NB256 * 4;                  // NB256*4
    int* pad_off  = boff + NB256 * 4;                      // 8
    int* deg     = pad_off + 8;                            // N  (deg, cursorD adjacent: one memset)
    int* cursorD = deg + N;                                // N
    int* off     = cursorD + N;                            // N
    int* bsum    = off + N;                                // NB+8
    int* elist   = bsum + NB + 8;                          // E
    float* aggr  = (float*)d_out;                          // aliases output (safe: see node_out)

    hipMemsetAsync(deg, 0, (size_t)(2 * N) * sizeof(int), stream);

    count_types_k<<<NB256, 256, 0, stream>>>(nt, blockcnt, N);
    scan_blocks_k<<<1, 256, 0, stream>>>(blockcnt, NB256, N, boff, pad_off, order_p);
    scatter_types_k<<<NB256, 256, 0, stream>>>(nt, boff, order_p, N);

    prep_weights_k<<<1024, 256, 0, stream>>>(Wk, Wq, Wv, Wa, bk, bv, rel_att, rel_msg,
                                             rel_pri, Wqt, Wat, Wkrt, Wvmt, bkr, bvm);

    deg_k<<<(E + 255) / 256, 256, 0, stream>>>(ei, deg, E);
    scan1_k<<<NB, 512, 0, stream>>>(deg, off, bsum, N);
    scan23_k<<<NB, 512, 0, stream>>>(off, bsum, N);
    scatter_edges_k<<<(E + 255) / 256, 256, 0, stream>>>(ei, et, off, cursorD, elist, E);

    int nb64 = (N + 252 + 63) / 64;
    proj_mfma<<<nb64, 256, 0, stream>>>(x, order_p, pad_off, Wqt, bq, Wkrt, bkr, Wvmt, bvm,
                                        Qb, KVb, N);
    int nquad = (N + 3) / 4;                       // one wave per 4 dsts
    edge_fused<<<(nquad + 3) / 4, 256, 0, stream>>>(Qb, KVb, off, elist, aggr, N, E);
    node_out_mfma<<<nb64, 256, 0, stream>>>(aggr, x, order_p, pad_off, Wat, ba, skip,
                                            gamma, beta, (float*)d_out, N);
}